// Round 4
// baseline (253.174 us; speedup 1.0000x reference)
//
#include <hip/hip_runtime.h>
#include <math.h>

#define BB    2
#define NN    1024
#define CSD   384
#define CZD   128
#define CZP   132     // padded LDS row (bank spread)
#define CHD   16
#define HH    12
#define PQD   4
#define PVD   8
#define KNB   50
#define HALFN 512
#define MTOK  (BB*NN)
#define LINW  1152
#define CATW  2112
#define OUT_SK 6
#define PROJB 288     // (2048/64) * (1152/128)

// ================= fused projection GEMM + top-K =================
// blocks [0, PROJB): lin = s @ [Wq|Wkv|Wqp|Wkvp]^T + bias  (64x128 tile, 4x8 micro)
// blocks [PROJB, PROJB+MTOK): radix-select top-50 neighbors (independent of proj)
__global__ __launch_bounds__(256) void proj_topk(
    const float* __restrict__ A,
    const float* __restrict__ Wq,  const float* __restrict__ bq,
    const float* __restrict__ Wkv, const float* __restrict__ bkv,
    const float* __restrict__ Wqp, const float* __restrict__ bqp,
    const float* __restrict__ Wkvp,const float* __restrict__ bkvp,
    float* __restrict__ lin,
    const float* __restrict__ trans,
    int* __restrict__ nidx)
{
    union SM {
        struct { float As[16][68]; float Bs[16][132]; } g;
        struct { float t3[3*NN]; unsigned long long keys[NN]; unsigned int hist[4][256]; } t;
    };
    __shared__ SM sm;
    __shared__ unsigned int warp_sums[4];
    __shared__ unsigned int s_seldig, s_selexc, s_selcnt, out_cnt;
    __shared__ unsigned long long s_pivot;
    __shared__ int s_done;

    const int tid = threadIdx.x;

    if (blockIdx.x < PROJB) {
        const int rowBase = (blockIdx.x & 31) * 64;
        const int colBase = (blockIdx.x >> 5) * 128;
        const int ar = tid >> 2, ak = (tid & 3) << 2;   // A loader: row, k-offset
        const int wc = tid >> 1, wk = (tid & 1) << 3;   // W loader: col, k-offset
        const float* aRow = A + (size_t)(rowBase + ar) * CSD + ak;
        const int gn = colBase + wc;
        const float* Wp; int wr;
        if      (gn < 192) { Wp = Wq;   wr = gn;       }
        else if (gn < 576) { Wp = Wkv;  wr = gn - 192; }
        else if (gn < 720) { Wp = Wqp;  wr = gn - 576; }
        else               { Wp = Wkvp; wr = gn - 720; }
        const float* wRow = Wp + (size_t)wr * CSD + wk;
        const int tm = (tid >> 4) << 2;   // 0..60
        const int tn = (tid & 15) << 3;   // 0..120
        float acc[4][8] = {};
        for (int k0 = 0; k0 < CSD; k0 += 16) {
            float4 av  = *(const float4*)(aRow + k0);
            float4 bv0 = *(const float4*)(wRow + k0);
            float4 bv1 = *(const float4*)(wRow + k0 + 4);
            __syncthreads();
            sm.g.As[ak+0][ar]=av.x;  sm.g.As[ak+1][ar]=av.y;
            sm.g.As[ak+2][ar]=av.z;  sm.g.As[ak+3][ar]=av.w;
            sm.g.Bs[wk+0][wc]=bv0.x; sm.g.Bs[wk+1][wc]=bv0.y;
            sm.g.Bs[wk+2][wc]=bv0.z; sm.g.Bs[wk+3][wc]=bv0.w;
            sm.g.Bs[wk+4][wc]=bv1.x; sm.g.Bs[wk+5][wc]=bv1.y;
            sm.g.Bs[wk+6][wc]=bv1.z; sm.g.Bs[wk+7][wc]=bv1.w;
            __syncthreads();
            #pragma unroll
            for (int kk = 0; kk < 16; ++kk) {
                float4 a4 = *(const float4*)&sm.g.As[kk][tm];
                float4 b0 = *(const float4*)&sm.g.Bs[kk][tn];
                float4 b1 = *(const float4*)&sm.g.Bs[kk][tn+4];
                float ar4[4] = {a4.x, a4.y, a4.z, a4.w};
                float br[8]  = {b0.x, b0.y, b0.z, b0.w, b1.x, b1.y, b1.z, b1.w};
                #pragma unroll
                for (int i = 0; i < 4; ++i)
                    #pragma unroll
                    for (int j = 0; j < 8; ++j)
                        acc[i][j] += ar4[i] * br[j];
            }
        }
        float bia[8];
        #pragma unroll
        for (int j = 0; j < 8; ++j) {
            int c = colBase + tn + j;
            if      (c < 192) bia[j] = bq[c];
            else if (c < 576) bia[j] = bkv[c-192];
            else if (c < 720) bia[j] = bqp[c-576];
            else              bia[j] = bkvp[c-720];
        }
        #pragma unroll
        for (int i = 0; i < 4; ++i) {
            int r = rowBase + tm + i;
            float4 o0 = {acc[i][0]+bia[0], acc[i][1]+bia[1], acc[i][2]+bia[2], acc[i][3]+bia[3]};
            float4 o1 = {acc[i][4]+bia[4], acc[i][5]+bia[5], acc[i][6]+bia[6], acc[i][7]+bia[7]};
            *(float4*)(lin + (size_t)r * LINW + colBase + tn)     = o0;
            *(float4*)(lin + (size_t)r * LINW + colBase + tn + 4) = o1;
        }
    } else {
        // ---- top-K radix select; only the SET matters (downstream is order-invariant)
        const int m = blockIdx.x - PROJB, b = m / NN, n = m % NN;
        const int lane = tid & 63, wid = tid >> 6;
        if (tid == 0) { s_done = 0; out_cnt = 0; }
        for (int i = tid; i < 3*NN; i += 256) sm.t.t3[i] = trans[(size_t)b*3*NN + i];
        __syncthreads();
        const float tx = sm.t.t3[n*3], ty = sm.t.t3[n*3+1], tz = sm.t.t3[n*3+2];
        for (int j = tid; j < NN; j += 256) {
            float dx = tx - sm.t.t3[j*3], dy = ty - sm.t.t3[j*3+1], dz = tz - sm.t.t3[j*3+2];
            float d = sqrtf(dx*dx + dy*dy + dz*dz);
            sm.t.keys[j] = ((unsigned long long)__float_as_uint(d) << 32) | (unsigned)j;
        }
        unsigned long long hi = 0;
        int rank = 0;
        const int target = KNB - 1;
        for (int d = 7; d >= 0; --d) {
            __syncthreads();
            if (s_done) break;
            const int shift = d * 8;
            for (int i = tid; i < 1024; i += 256) ((unsigned int*)sm.t.hist)[i] = 0;
            __syncthreads();
            for (int j = tid; j < NN; j += 256) {
                unsigned long long key = sm.t.keys[j];
                bool match = (d == 7) || ((key >> (shift + 8)) == hi);
                if (match) atomicAdd(&sm.t.hist[wid][(unsigned)(key >> shift) & 0xffu], 1u);
            }
            __syncthreads();
            unsigned int v = sm.t.hist[0][tid] + sm.t.hist[1][tid]
                           + sm.t.hist[2][tid] + sm.t.hist[3][tid];
            unsigned int inc = v;
            #pragma unroll
            for (int off = 1; off < 64; off <<= 1) {
                unsigned int nv = __shfl_up(inc, off);
                if (lane >= off) inc += nv;
            }
            if (lane == 63) warp_sums[wid] = inc;
            __syncthreads();
            unsigned int woff = 0;
            for (int w = 0; w < wid; ++w) woff += warp_sums[w];
            unsigned int exc = woff + inc - v;
            int t = target - rank;
            if ((int)exc <= t && t < (int)(exc + v)) {
                s_seldig = (unsigned)tid; s_selexc = exc; s_selcnt = v;
            }
            __syncthreads();
            hi = (hi << 8) | (unsigned long long)s_seldig;
            rank += (int)s_selexc;
            if (s_selcnt == 1u) {
                for (int j = tid; j < NN; j += 256) {
                    unsigned long long key = sm.t.keys[j];
                    if ((key >> shift) == hi) s_pivot = key;
                }
                if (tid == 0) s_done = 1;
            } else if (d == 0) {
                if (tid == 0) { s_pivot = hi; s_done = 1; }
            }
        }
        __syncthreads();
        const unsigned long long pivot = s_pivot;
        for (int j = tid; j < NN; j += 256) {
            unsigned long long key = sm.t.keys[j];
            if (key <= pivot) {
                unsigned p = atomicAdd(&out_cnt, 1u);
                nidx[(size_t)m * KNB + p] = (int)(key & 0xffffffffu);
            }
        }
    }
}

// ------------- split-K out-GEMM (64x128 tile, 4x8 micro) -------------
__global__ __launch_bounds__(256) void gemm_out(
    const float* __restrict__ A, const float* __restrict__ W,
    float* __restrict__ parts)
{
    __shared__ float As[16][68];
    __shared__ float Bs[16][132];
    const int tid = threadIdx.x;
    const int rowBase = blockIdx.x * 64;
    const int colBase = blockIdx.y * 128;
    const int k0s = blockIdx.z * (CATW / OUT_SK);
    const int ar = tid >> 2, ak = (tid & 3) << 2;
    const int wc = tid >> 1, wk = (tid & 1) << 3;
    const float* aRow = A + (size_t)(rowBase + ar) * CATW + k0s + ak;
    const float* wRow = W + (size_t)(colBase + wc) * CATW + k0s + wk;
    const int tm = (tid >> 4) << 2;
    const int tn = (tid & 15) << 3;
    float acc[4][8] = {};
    for (int k0 = 0; k0 < CATW / OUT_SK; k0 += 16) {
        float4 av  = *(const float4*)(aRow + k0);
        float4 bv0 = *(const float4*)(wRow + k0);
        float4 bv1 = *(const float4*)(wRow + k0 + 4);
        __syncthreads();
        As[ak+0][ar]=av.x;  As[ak+1][ar]=av.y;  As[ak+2][ar]=av.z;  As[ak+3][ar]=av.w;
        Bs[wk+0][wc]=bv0.x; Bs[wk+1][wc]=bv0.y; Bs[wk+2][wc]=bv0.z; Bs[wk+3][wc]=bv0.w;
        Bs[wk+4][wc]=bv1.x; Bs[wk+5][wc]=bv1.y; Bs[wk+6][wc]=bv1.z; Bs[wk+7][wc]=bv1.w;
        __syncthreads();
        #pragma unroll
        for (int kk = 0; kk < 16; ++kk) {
            float4 a4 = *(const float4*)&As[kk][tm];
            float4 b0 = *(const float4*)&Bs[kk][tn];
            float4 b1 = *(const float4*)&Bs[kk][tn+4];
            float ar4[4] = {a4.x, a4.y, a4.z, a4.w};
            float br[8]  = {b0.x, b0.y, b0.z, b0.w, b1.x, b1.y, b1.z, b1.w};
            #pragma unroll
            for (int i = 0; i < 4; ++i)
                #pragma unroll
                for (int j = 0; j < 8; ++j)
                    acc[i][j] += ar4[i] * br[j];
        }
    }
    float* dst = parts + (size_t)blockIdx.z * MTOK * 384;
    #pragma unroll
    for (int i = 0; i < 4; ++i) {
        int r = rowBase + tm + i;
        float4 o0 = {acc[i][0], acc[i][1], acc[i][2], acc[i][3]};
        float4 o1 = {acc[i][4], acc[i][5], acc[i][6], acc[i][7]};
        *(float4*)(dst + (size_t)r * 384 + colBase + tn)     = o0;
        *(float4*)(dst + (size_t)r * 384 + colBase + tn + 4) = o1;
    }
}

__global__ __launch_bounds__(256) void reduce_splitk(
    const float* __restrict__ parts, const float* __restrict__ bias,
    float* __restrict__ out)
{
    const int i4 = blockIdx.x * 256 + threadIdx.x;   // float4 index
    const int TOT4 = MTOK * 384 / 4;
    if (i4 >= TOT4) return;
    const int c4 = i4 % (384 / 4);
    float4 acc = *(const float4*)(bias + c4 * 4);
    #pragma unroll
    for (int s = 0; s < OUT_SK; ++s) {
        float4 p = *(const float4*)(parts + (size_t)s * MTOK * 384 + (size_t)i4 * 4);
        acc.x += p.x; acc.y += p.y; acc.z += p.z; acc.w += p.w;
    }
    *(float4*)(out + (size_t)i4 * 4) = acc;
}

// ------------- point transform: rot @ p + trans -------------
__global__ void point_transform(const float* __restrict__ lin,
                                const float* __restrict__ rot,
                                const float* __restrict__ trans,
                                float* __restrict__ q_pts,
                                float* __restrict__ k_pts,
                                float* __restrict__ v_pts)
{
    const int m = blockIdx.x;
    const int j = threadIdx.x;   // 0..191
    const float* R = rot + (size_t)m * 9;
    const float* T = trans + (size_t)m * 3;
    const float* L = lin + (size_t)m * LINW;
    float p0, p1, p2;
    if (j < 48) {
        p0 = L[576 + j]; p1 = L[576 + 48 + j]; p2 = L[576 + 96 + j];
    } else {
        int j2 = j - 48;                     // 0..143
        p0 = L[720 + j2]; p1 = L[720 + 144 + j2]; p2 = L[720 + 288 + j2];
    }
    float ox = R[0]*p0 + R[1]*p1 + R[2]*p2 + T[0];
    float oy = R[3]*p0 + R[4]*p1 + R[5]*p2 + T[1];
    float oz = R[6]*p0 + R[7]*p1 + R[8]*p2 + T[2];
    if (j < 48) {
        float* o = q_pts + (size_t)m * 144 + 3 * j;
        o[0] = ox; o[1] = oy; o[2] = oz;
    } else {
        int j2 = j - 48, h = j2 / 12, pp = j2 % 12;
        if (pp < PQD) {
            float* o = k_pts + (size_t)m * 144 + ((h*PQD + pp) * 3);
            o[0] = ox; o[1] = oy; o[2] = oz;
        } else {
            float* o = v_pts + (size_t)m * 288 + ((h*PVD + pp - PQD) * 3);
            o[0] = ox; o[1] = oy; o[2] = oz;
        }
    }
}

// ------------- attention per token -------------
__global__ __launch_bounds__(256) void attn_kernel(
    const float* __restrict__ lin,     // q at +0, kv at +192 (per 1152-row)
    const float* __restrict__ q_pts,
    const float* __restrict__ k_pts,
    const float* __restrict__ v_pts,
    const int*   __restrict__ nidx,
    const float* __restrict__ z,       // (B, 512, 512, 128)
    const float* __restrict__ Wb,      // (12, 128)
    const float* __restrict__ bbv,     // (12)
    const float* __restrict__ hwin,    // (12)
    const float* __restrict__ mask,    // (B, N)
    const float* __restrict__ rot,
    const float* __restrict__ trans,
    float* __restrict__ cat)           // (M, 2112)
{
    __shared__ __align__(16) float zn[KNB][CZP];     // 26.4 KB, padded rows
    __shared__ __align__(16) float WbS[HH][CZP];     // 6.3 KB
    __shared__ float aP[HH][KNB + 2];
    __shared__ __align__(16) float qloc[192];
    __shared__ __align__(16) float qp[144];
    __shared__ int   nk[KNB];
    __shared__ float maskn[KNB];
    __shared__ float hwS[HH];
    __shared__ __align__(16) float opt[288];

    const int m = blockIdx.x;
    const int b = m / NN, n = m % NN;
    const int tid = threadIdx.x;
    const int lane = tid & 63, wid = tid >> 6;

    if (tid < KNB) nk[tid] = nidx[(size_t)m * KNB + tid];
    __syncthreads();

    for (int i = tid; i < HH * CZD; i += 256) WbS[i / CZD][i % CZD] = Wb[i];
    for (int i = tid; i < 192; i += 256) qloc[i] = lin[(size_t)m * LINW + i];
    for (int i = tid; i < 144; i += 256) qp[i] = q_pts[(size_t)m * 144 + i];
    if (tid < HH) hwS[tid] = log1pf(expf(hwin[tid])) * 0.13608276348795434f; // sqrt(1/54)
    if (tid < KNB) maskn[tid] = 100000.0f * (mask[m] * mask[(size_t)b * NN + nk[tid]] - 1.0f);
    {
        // float4 z gather: each wave covers 2 rows/iter (32 lanes * float4 = 128 floats)
        const int sub = lane >> 5, l32 = lane & 31;
        for (int k = wid * 2 + sub; k < KNB; k += 8) {
            const float* zr = z + (((size_t)b * HALFN + (n & (HALFN-1))) * HALFN + (nk[k] & (HALFN-1))) * CZD;
            float4 v4 = *(const float4*)(zr + l32 * 4);
            *(float4*)&zn[k][l32 * 4] = v4;
        }
    }
    __syncthreads();

    // logits
    for (int idx = tid; idx < HH * KNB; idx += 256) {
        int k = idx / HH, h = idx % HH;
        int mk = b * NN + nk[k];
        const float* kvr = lin + (size_t)mk * LINW + 192 + h * 32;
        float qk = 0.f;
        #pragma unroll
        for (int c4 = 0; c4 < 4; ++c4) {
            float4 kv4 = *(const float4*)(kvr + c4 * 4);
            float4 q4  = *(const float4*)&qloc[h * 16 + c4 * 4];
            qk += q4.x*kv4.x + q4.y*kv4.y + q4.z*kv4.z + q4.w*kv4.w;
        }
        const float* kpr = k_pts + (size_t)mk * 144 + h * 12;
        float kp[12], qv[12];
        *(float4*)&kp[0] = *(const float4*)(kpr);
        *(float4*)&kp[4] = *(const float4*)(kpr + 4);
        *(float4*)&kp[8] = *(const float4*)(kpr + 8);
        *(float4*)&qv[0] = *(const float4*)&qp[h*12];
        *(float4*)&qv[4] = *(const float4*)&qp[h*12 + 4];
        *(float4*)&qv[8] = *(const float4*)&qp[h*12 + 8];
        float d2s = 0.f;
        #pragma unroll
        for (int e = 0; e < 12; ++e) { float dd = qv[e] - kp[e]; d2s += dd*dd; }
        float4 acc4 = {0.f, 0.f, 0.f, 0.f};
        #pragma unroll 8
        for (int c4 = 0; c4 < 32; ++c4) {
            float4 z4 = *(const float4*)&zn[k][c4 * 4];
            float4 w4 = *(const float4*)&WbS[h][c4 * 4];
            acc4.x += z4.x*w4.x; acc4.y += z4.y*w4.y;
            acc4.z += z4.z*w4.z; acc4.w += z4.w*w4.w;
        }
        float bp = bbv[h] + acc4.x + acc4.y + acc4.z + acc4.w;
        aP[h][k] = qk * 0.14433756729740643f      // sqrt(1/(3*16))
                 + 0.5773502691896258f * bp       // sqrt(1/3)
                 - 0.5f * hwS[h] * d2s
                 + maskn[k];
    }
    __syncthreads();

    // softmax over k per head (wave-parallel, lanes 0..49 hold values)
    for (int h = wid; h < HH; h += 4) {
        float v = (lane < KNB) ? aP[h][lane] : -1e30f;
        float mx = v;
        #pragma unroll
        for (int off = 32; off; off >>= 1) mx = fmaxf(mx, __shfl_xor(mx, off));
        float e = (lane < KNB) ? expf(v - mx) : 0.f;
        float s = e;
        #pragma unroll
        for (int off = 32; off; off >>= 1) s += __shfl_xor(s, off);
        if (lane < KNB) aP[h][lane] = e / s;
    }
    __syncthreads();

    // o (48 float4) and o_pt raw (72 float4)
    if (tid < 120) {
        float4 acc = {0.f, 0.f, 0.f, 0.f};
        if (tid < 48) {
            int h = tid >> 2, c4 = tid & 3;
            for (int k = 0; k < KNB; ++k) {
                int mk = b * NN + nk[k];
                float4 v4 = *(const float4*)(lin + (size_t)mk * LINW + 192 + h*32 + 16 + c4*4);
                float a = aP[h][k];
                acc.x += a*v4.x; acc.y += a*v4.y; acc.z += a*v4.z; acc.w += a*v4.w;
            }
            *(float4*)(cat + (size_t)m * CATW + tid * 4) = acc;
        } else {
            int u2 = tid - 48;                   // 0..71
            int h = (u2 * 4) / 24, r = (u2 * 4) % 24;
            for (int k = 0; k < KNB; ++k) {
                int mk = b * NN + nk[k];
                float4 v4 = *(const float4*)(v_pts + (size_t)mk * 288 + h*24 + r);
                float a = aP[h][k];
                acc.x += a*v4.x; acc.y += a*v4.y; acc.z += a*v4.z; acc.w += a*v4.w;
            }
            *(float4*)&opt[u2 * 4] = acc;
        }
    }
    __syncthreads();

    // inverse frame transform + norm
    if (tid < 96) {
        int hp = tid;
        float x = opt[hp*3+0] - trans[(size_t)m*3+0];
        float y = opt[hp*3+1] - trans[(size_t)m*3+1];
        float z0 = opt[hp*3+2] - trans[(size_t)m*3+2];
        const float* R = rot + (size_t)m * 9;
        float o0 = R[0]*x + R[3]*y + R[6]*z0;   // rot^T
        float o1 = R[1]*x + R[4]*y + R[7]*z0;
        float o2 = R[2]*x + R[5]*y + R[8]*z0;
        float nrm = sqrtf(o0*o0 + o1*o1 + o2*o2 + 1e-8f);
        float* c0 = cat + (size_t)m * CATW;
        c0[192 + hp] = o0;
        c0[288 + hp] = o1;
        c0[384 + hp] = o2;
        c0[480 + hp] = nrm;
    }

    // o_pair: 12 heads x 32 float4 columns from LDS zn
    for (int u = tid; u < HH * 32; u += 256) {
        int h = u >> 5, c4 = u & 31;
        float4 acc = {0.f, 0.f, 0.f, 0.f};
        for (int k = 0; k < KNB; ++k) {
            float a = aP[h][k];
            float4 z4 = *(const float4*)&zn[k][c4 * 4];
            acc.x += a*z4.x; acc.y += a*z4.y; acc.z += a*z4.z; acc.w += a*z4.w;
        }
        *(float4*)(cat + (size_t)m * CATW + 576 + h * 128 + c4 * 4) = acc;
    }
}

extern "C" void kernel_launch(void* const* d_in, const int* in_sizes, int n_in,
                              void* d_out, int out_size, void* d_ws, size_t ws_size,
                              hipStream_t stream) {
    const float* s     = (const float*)d_in[0];
    const float* z     = (const float*)d_in[1];
    const float* rot   = (const float*)d_in[2];
    const float* trans = (const float*)d_in[3];
    const float* mask  = (const float*)d_in[4];
    // d_in[5] rel_pos unused
    const float* Wq    = (const float*)d_in[6];
    const float* bq    = (const float*)d_in[7];
    const float* Wkv   = (const float*)d_in[8];
    const float* bkv   = (const float*)d_in[9];
    const float* Wqp   = (const float*)d_in[10];
    const float* bqp   = (const float*)d_in[11];
    const float* Wkvp  = (const float*)d_in[12];
    const float* bkvp  = (const float*)d_in[13];
    const float* Wb    = (const float*)d_in[14];
    const float* bb    = (const float*)d_in[15];
    const float* hw    = (const float*)d_in[16];
    const float* Wout  = (const float*)d_in[17];
    const float* bout  = (const float*)d_in[18];
    float* out = (float*)d_out;

    float* ws    = (float*)d_ws;
    float* lin   = ws;                              // 2048*1152
    float* qpts  = lin  + (size_t)MTOK * LINW;      // 2048*144
    float* kpts  = qpts + (size_t)MTOK * 144;       // 2048*144
    float* vpts  = kpts + (size_t)MTOK * 144;       // 2048*288
    int*   nidxb = (int*)(vpts + (size_t)MTOK * 288);
    float* cat   = (float*)(nidxb + (size_t)MTOK * KNB); // 2048*2112
    float* parts = cat + (size_t)MTOK * CATW;       // OUT_SK * 2048*384

    proj_topk<<<PROJB + MTOK, 256, 0, stream>>>(s, Wq, bq, Wkv, bkv, Wqp, bqp,
                                                Wkvp, bkvp, lin, trans, nidxb);
    point_transform<<<MTOK, 192, 0, stream>>>(lin, rot, trans, qpts, kpts, vpts);
    attn_kernel<<<MTOK, 256, 0, stream>>>(lin, qpts, kpts, vpts, nidxb, z, Wb, bb, hw,
                                          mask, rot, trans, cat);
    dim3 g2(MTOK / 64, 384 / 128, OUT_SK);
    gemm_out<<<g2, 256, 0, stream>>>(cat, Wout, parts);
    reduce_splitk<<<(MTOK * 384 / 4 + 255) / 256, 256, 0, stream>>>(parts, bout, out);
}

// Round 6
// 162.008 us; speedup vs baseline: 1.5627x; 1.5627x over previous
//
#include <hip/hip_runtime.h>
#include <math.h>

#define BB    2
#define NN    1024
#define CSD   384
#define CZD   128
#define CZP   132     // padded LDS row (bank spread)
#define CHD   16
#define HH    12
#define PQD   4
#define PVD   8
#define KNB   50
#define HALFN 512
#define MTOK  (BB*NN)
#define LINW  1152
#define CATW  2112
#define OSK   3       // split-K for bf16 out-GEMM
#define OKSTEP (CATW / OSK)   // 704

typedef __attribute__((ext_vector_type(8))) short    bf16x8;
typedef __attribute__((ext_vector_type(4))) float    f32x4;
typedef __attribute__((ext_vector_type(4))) unsigned short us4;

// fp32 -> bf16 round-to-nearest-even (finite inputs; no header dependency)
static __device__ __forceinline__ unsigned short f2b(float x) {
    unsigned u = __float_as_uint(x);
    unsigned rnd = 0x7fffu + ((u >> 16) & 1u);
    return (unsigned short)((u + rnd) >> 16);
}

// ---------------- projection GEMM (round-3 proven 64x64 tile) ----------------
__global__ __launch_bounds__(256) void proj_gemm(
    const float* __restrict__ A,
    const float* __restrict__ Wq,  const float* __restrict__ bq,
    const float* __restrict__ Wkv, const float* __restrict__ bkv,
    const float* __restrict__ Wqp, const float* __restrict__ bqp,
    const float* __restrict__ Wkvp,const float* __restrict__ bkvp,
    float* __restrict__ lin)
{
    __shared__ float As[16][68];
    __shared__ float Bs[16][68];
    const int tid = threadIdx.x;
    const int tm = tid >> 4, tn = tid & 15;
    const int rowBase = blockIdx.x * 64, colBase = blockIdx.y * 64;
    const int lm = tid >> 2;
    const int lk = (tid & 3) << 2;
    const float* aRow = A + (size_t)(rowBase + lm) * CSD;
    int gn = colBase + lm;
    const float* Wp; int wr;
    if      (gn < 192) { Wp = Wq;   wr = gn;       }
    else if (gn < 576) { Wp = Wkv;  wr = gn - 192; }
    else if (gn < 720) { Wp = Wqp;  wr = gn - 576; }
    else               { Wp = Wkvp; wr = gn - 720; }
    const float* wRow = Wp + (size_t)wr * CSD;
    float acc[4][4] = {};
    for (int k0 = 0; k0 < CSD; k0 += 16) {
        float4 av = *(const float4*)(aRow + k0 + lk);
        float4 bv = *(const float4*)(wRow + k0 + lk);
        __syncthreads();
        As[lk+0][lm] = av.x; As[lk+1][lm] = av.y; As[lk+2][lm] = av.z; As[lk+3][lm] = av.w;
        Bs[lk+0][lm] = bv.x; Bs[lk+1][lm] = bv.y; Bs[lk+2][lm] = bv.z; Bs[lk+3][lm] = bv.w;
        __syncthreads();
        #pragma unroll
        for (int kk = 0; kk < 16; ++kk) {
            float4 a4 = *(const float4*)&As[kk][tm*4];
            float4 b4 = *(const float4*)&Bs[kk][tn*4];
            float ar[4] = {a4.x, a4.y, a4.z, a4.w};
            float br[4] = {b4.x, b4.y, b4.z, b4.w};
            #pragma unroll
            for (int i = 0; i < 4; ++i)
                #pragma unroll
                for (int j = 0; j < 4; ++j)
                    acc[i][j] += ar[i] * br[j];
        }
    }
    float bia[4];
    #pragma unroll
    for (int j = 0; j < 4; ++j) {
        int c = colBase + tn*4 + j;
        if      (c < 192) bia[j] = bq[c];
        else if (c < 576) bia[j] = bkv[c-192];
        else if (c < 720) bia[j] = bqp[c-576];
        else              bia[j] = bkvp[c-720];
    }
    #pragma unroll
    for (int i = 0; i < 4; ++i) {
        int r = rowBase + tm*4 + i;
        float4 o;
        o.x = acc[i][0] + bia[0]; o.y = acc[i][1] + bia[1];
        o.z = acc[i][2] + bia[2]; o.w = acc[i][3] + bia[3];
        *(float4*)(lin + (size_t)r * LINW + colBase + tn*4) = o;
    }
}

// ------------- Wout fp32 -> bf16 -------------
__global__ __launch_bounds__(256) void convert_wout(const float* __restrict__ W,
                                                    unsigned short* __restrict__ wb)
{
    const int i = blockIdx.x * 256 + threadIdx.x;   // float4 index
    const int TOT = 384 * CATW / 4;
    if (i >= TOT) return;
    float4 v = *(const float4*)(W + (size_t)i * 4);
    us4 o = { f2b(v.x), f2b(v.y), f2b(v.z), f2b(v.w) };
    *(us4*)(wb + (size_t)i * 4) = o;
}

// ------------- bf16 MFMA out-GEMM: parts[z] = catb @ wob^T over k-chunk -------------
// 128x64 tile, 4 waves (2x2), each wave 64x32 via 4x2 fragments of 16x16x32.
__global__ __launch_bounds__(256) void gemm_out_mfma(
    const unsigned short* __restrict__ catb,   // (2048, 2112) bf16
    const unsigned short* __restrict__ wob,    // (384, 2112) bf16
    float* __restrict__ parts)
{
    __shared__ unsigned short As[128][40];   // stride 40 shorts (80B): 2-way-free banks
    __shared__ unsigned short Bs[64][40];
    const int tid = threadIdx.x;
    const int lane = tid & 63, wv = tid >> 6;
    const int wr = wv >> 1, wc = wv & 1;
    const int rowBase = blockIdx.x * 128;
    const int colBase = blockIdx.y * 64;
    const int k0s = blockIdx.z * OKSTEP;
    const int sr = tid >> 2;                 // 0..63
    const int sq = (tid & 3) * 8;            // k offset (bf16)
    const unsigned short* aRow0 = catb + (size_t)(rowBase + sr) * CATW + k0s + sq;
    const unsigned short* aRow1 = catb + (size_t)(rowBase + 64 + sr) * CATW + k0s + sq;
    const unsigned short* bRow  = wob  + (size_t)(colBase + sr) * CATW + k0s + sq;

    f32x4 acc[4][2];
    #pragma unroll
    for (int i = 0; i < 4; ++i)
        #pragma unroll
        for (int j = 0; j < 2; ++j)
            acc[i][j] = (f32x4){0.f, 0.f, 0.f, 0.f};

    const int kg = (lane >> 4) * 8;          // k-chunk of this lane
    const int rr = lane & 15;

    for (int k0 = 0; k0 < OKSTEP; k0 += 32) {
        bf16x8 a0 = *(const bf16x8*)(aRow0 + k0);
        bf16x8 a1 = *(const bf16x8*)(aRow1 + k0);
        bf16x8 b0 = *(const bf16x8*)(bRow  + k0);
        __syncthreads();
        *(bf16x8*)&As[sr][sq]      = a0;
        *(bf16x8*)&As[64 + sr][sq] = a1;
        *(bf16x8*)&Bs[sr][sq]      = b0;
        __syncthreads();
        bf16x8 bfr[2], afr[4];
        #pragma unroll
        for (int fc = 0; fc < 2; ++fc)
            bfr[fc] = *(const bf16x8*)&Bs[wc*32 + fc*16 + rr][kg];
        #pragma unroll
        for (int fr = 0; fr < 4; ++fr)
            afr[fr] = *(const bf16x8*)&As[wr*64 + fr*16 + rr][kg];
        #pragma unroll
        for (int fr = 0; fr < 4; ++fr)
            #pragma unroll
            for (int fc = 0; fc < 2; ++fc)
                acc[fr][fc] = __builtin_amdgcn_mfma_f32_16x16x32_bf16(
                    afr[fr], bfr[fc], acc[fr][fc], 0, 0, 0);
    }

    float* dst = parts + (size_t)blockIdx.z * MTOK * 384;
    const int cRowL = (lane >> 4) * 4;       // C/D: row=(lane>>4)*4+reg, col=lane&15
    const int cColL = lane & 15;
    #pragma unroll
    for (int fr = 0; fr < 4; ++fr) {
        #pragma unroll
        for (int fc = 0; fc < 2; ++fc) {
            int col = colBase + wc*32 + fc*16 + cColL;
            int row0 = rowBase + wr*64 + fr*16 + cRowL;
            #pragma unroll
            for (int g = 0; g < 4; ++g)
                dst[(size_t)(row0 + g) * 384 + col] = acc[fr][fc][g];
        }
    }
}

__global__ __launch_bounds__(256) void reduce_splitk(
    const float* __restrict__ parts, const float* __restrict__ bias,
    float* __restrict__ out)
{
    const int i4 = blockIdx.x * 256 + threadIdx.x;   // float4 index
    const int TOT4 = MTOK * 384 / 4;
    if (i4 >= TOT4) return;
    const int c4 = i4 % (384 / 4);
    float4 acc = *(const float4*)(bias + c4 * 4);
    #pragma unroll
    for (int s = 0; s < OSK; ++s) {
        float4 p = *(const float4*)(parts + (size_t)s * MTOK * 384 + (size_t)i4 * 4);
        acc.x += p.x; acc.y += p.y; acc.z += p.z; acc.w += p.w;
    }
    *(float4*)(out + (size_t)i4 * 4) = acc;
}

// ------------- point transform: rot @ p + trans -------------
__global__ void point_transform(const float* __restrict__ lin,
                                const float* __restrict__ rot,
                                const float* __restrict__ trans,
                                float* __restrict__ q_pts,
                                float* __restrict__ k_pts,
                                float* __restrict__ v_pts)
{
    const int m = blockIdx.x;
    const int j = threadIdx.x;   // 0..191
    const float* R = rot + (size_t)m * 9;
    const float* T = trans + (size_t)m * 3;
    const float* L = lin + (size_t)m * LINW;
    float p0, p1, p2;
    if (j < 48) {
        p0 = L[576 + j]; p1 = L[576 + 48 + j]; p2 = L[576 + 96 + j];
    } else {
        int j2 = j - 48;                     // 0..143
        p0 = L[720 + j2]; p1 = L[720 + 144 + j2]; p2 = L[720 + 288 + j2];
    }
    float ox = R[0]*p0 + R[1]*p1 + R[2]*p2 + T[0];
    float oy = R[3]*p0 + R[4]*p1 + R[5]*p2 + T[1];
    float oz = R[6]*p0 + R[7]*p1 + R[8]*p2 + T[2];
    if (j < 48) {
        float* o = q_pts + (size_t)m * 144 + 3 * j;
        o[0] = ox; o[1] = oy; o[2] = oz;
    } else {
        int j2 = j - 48, h = j2 / 12, pp = j2 % 12;
        if (pp < PQD) {
            float* o = k_pts + (size_t)m * 144 + ((h*PQD + pp) * 3);
            o[0] = ox; o[1] = oy; o[2] = oz;
        } else {
            float* o = v_pts + (size_t)m * 288 + ((h*PVD + pp - PQD) * 3);
            o[0] = ox; o[1] = oy; o[2] = oz;
        }
    }
}

// ------------- top-K neighbors via radix-select (d^2 key; set is order-invariant) -------------
__global__ __launch_bounds__(256) void topk_kernel(const float* __restrict__ trans,
                                                   int* __restrict__ nidx)
{
    __shared__ float t3[3 * NN];
    __shared__ unsigned long long keys[NN];
    __shared__ unsigned int hist[256];
    __shared__ unsigned int warp_sums[4];
    __shared__ unsigned int s_seldig, s_selexc, s_selcnt, out_cnt;
    __shared__ unsigned long long s_pivot;
    __shared__ int s_done;

    const int m = blockIdx.x, b = m / NN, n = m % NN, tid = threadIdx.x;
    const int lane = tid & 63, wid = tid >> 6;

    if (tid == 0) { s_done = 0; out_cnt = 0; }
    for (int i = tid; i < 3 * NN; i += 256) t3[i] = trans[(size_t)b * 3 * NN + i];
    __syncthreads();
    const float tx = t3[n*3], ty = t3[n*3+1], tz = t3[n*3+2];
    for (int j = tid; j < NN; j += 256) {
        float dx = tx - t3[j*3], dy = ty - t3[j*3+1], dz = tz - t3[j*3+2];
        float d = dx*dx + dy*dy + dz*dz;          // rank-equivalent to sqrt
        keys[j] = ((unsigned long long)__float_as_uint(d) << 32) | (unsigned)j;
    }

    unsigned long long hi = 0;
    int rank = 0;
    const int target = KNB - 1;
    for (int d = 7; d >= 0; --d) {
        __syncthreads();
        if (s_done) break;
        const int shift = d * 8;
        hist[tid] = 0;
        __syncthreads();
        for (int j = tid; j < NN; j += 256) {
            unsigned long long key = keys[j];
            bool match = (d == 7) || ((key >> (shift + 8)) == hi);
            if (match) atomicAdd(&hist[(unsigned)(key >> shift) & 0xffu], 1u);
        }
        __syncthreads();
        unsigned int v = hist[tid];
        unsigned int inc = v;
        #pragma unroll
        for (int off = 1; off < 64; off <<= 1) {
            unsigned int nv = __shfl_up(inc, off);
            if (lane >= off) inc += nv;
        }
        if (lane == 63) warp_sums[wid] = inc;
        __syncthreads();
        unsigned int woff = 0;
        for (int w = 0; w < wid; ++w) woff += warp_sums[w];
        unsigned int exc = woff + inc - v;
        int t = target - rank;
        if ((int)exc <= t && t < (int)(exc + v)) {
            s_seldig = (unsigned)tid; s_selexc = exc; s_selcnt = v;
        }
        __syncthreads();
        hi = (hi << 8) | (unsigned long long)s_seldig;
        rank += (int)s_selexc;
        if (s_selcnt == 1u) {
            for (int j = tid; j < NN; j += 256) {
                unsigned long long key = keys[j];
                if ((key >> shift) == hi) s_pivot = key;
            }
            if (tid == 0) s_done = 1;
        } else if (d == 0) {
            if (tid == 0) { s_pivot = hi; s_done = 1; }
        }
    }
    __syncthreads();
    const unsigned long long pivot = s_pivot;
    for (int j = tid; j < NN; j += 256) {
        unsigned long long key = keys[j];
        if (key <= pivot) {
            unsigned p = atomicAdd(&out_cnt, 1u);
            nidx[(size_t)m * KNB + p] = (int)(key & 0xffffffffu);
        }
    }
}

// ------------- attention per token (writes cat in bf16) -------------
__global__ __launch_bounds__(256) void attn_kernel(
    const float* __restrict__ lin,     // q at +0, kv at +192 (per 1152-row)
    const float* __restrict__ q_pts,
    const float* __restrict__ k_pts,
    const float* __restrict__ v_pts,
    const int*   __restrict__ nidx,
    const float* __restrict__ z,       // (B, 512, 512, 128)
    const float* __restrict__ Wb,      // (12, 128)
    const float* __restrict__ bbv,     // (12)
    const float* __restrict__ hwin,    // (12)
    const float* __restrict__ mask,    // (B, N)
    const float* __restrict__ rot,
    const float* __restrict__ trans,
    unsigned short* __restrict__ cat)  // (M, 2112) bf16
{
    __shared__ __align__(16) float zn[KNB][CZP];     // 26.4 KB, padded rows
    __shared__ __align__(16) float WbS[HH][CZP];     // 6.3 KB
    __shared__ float aP[HH][KNB + 2];
    __shared__ __align__(16) float qloc[192];
    __shared__ __align__(16) float qp[144];
    __shared__ int   nk[KNB];
    __shared__ float maskn[KNB];
    __shared__ float hwS[HH];
    __shared__ __align__(16) float opt[288];

    const int m = blockIdx.x;
    const int b = m / NN, n = m % NN;
    const int tid = threadIdx.x;
    const int lane = tid & 63, wid = tid >> 6;

    if (tid < KNB) nk[tid] = nidx[(size_t)m * KNB + tid];
    __syncthreads();

    for (int i = tid; i < HH * CZD; i += 256) WbS[i / CZD][i % CZD] = Wb[i];
    for (int i = tid; i < 192; i += 256) qloc[i] = lin[(size_t)m * LINW + i];
    for (int i = tid; i < 144; i += 256) qp[i] = q_pts[(size_t)m * 144 + i];
    if (tid < HH) hwS[tid] = log1pf(expf(hwin[tid])) * 0.13608276348795434f; // sqrt(1/54)
    if (tid < KNB) maskn[tid] = 100000.0f * (mask[m] * mask[(size_t)b * NN + nk[tid]] - 1.0f);
    {
        const int sub = lane >> 5, l32 = lane & 31;
        for (int k = wid * 2 + sub; k < KNB; k += 8) {
            const float* zr = z + (((size_t)b * HALFN + (n & (HALFN-1))) * HALFN + (nk[k] & (HALFN-1))) * CZD;
            float4 v4 = *(const float4*)(zr + l32 * 4);
            *(float4*)&zn[k][l32 * 4] = v4;
        }
    }
    __syncthreads();

    // logits
    for (int idx = tid; idx < HH * KNB; idx += 256) {
        int k = idx / HH, h = idx % HH;
        int mk = b * NN + nk[k];
        const float* kvr = lin + (size_t)mk * LINW + 192 + h * 32;
        float qk = 0.f;
        #pragma unroll
        for (int c4 = 0; c4 < 4; ++c4) {
            float4 kv4 = *(const float4*)(kvr + c4 * 4);
            float4 q4  = *(const float4*)&qloc[h * 16 + c4 * 4];
            qk += q4.x*kv4.x + q4.y*kv4.y + q4.z*kv4.z + q4.w*kv4.w;
        }
        const float* kpr = k_pts + (size_t)mk * 144 + h * 12;
        float kp[12], qv[12];
        *(float4*)&kp[0] = *(const float4*)(kpr);
        *(float4*)&kp[4] = *(const float4*)(kpr + 4);
        *(float4*)&kp[8] = *(const float4*)(kpr + 8);
        *(float4*)&qv[0] = *(const float4*)&qp[h*12];
        *(float4*)&qv[4] = *(const float4*)&qp[h*12 + 4];
        *(float4*)&qv[8] = *(const float4*)&qp[h*12 + 8];
        float d2s = 0.f;
        #pragma unroll
        for (int e = 0; e < 12; ++e) { float dd = qv[e] - kp[e]; d2s += dd*dd; }
        float4 acc4 = {0.f, 0.f, 0.f, 0.f};
        #pragma unroll 8
        for (int c4 = 0; c4 < 32; ++c4) {
            float4 z4 = *(const float4*)&zn[k][c4 * 4];
            float4 w4 = *(const float4*)&WbS[h][c4 * 4];
            acc4.x += z4.x*w4.x; acc4.y += z4.y*w4.y;
            acc4.z += z4.z*w4.z; acc4.w += z4.w*w4.w;
        }
        float bp = bbv[h] + acc4.x + acc4.y + acc4.z + acc4.w;
        aP[h][k] = qk * 0.14433756729740643f      // sqrt(1/(3*16))
                 + 0.5773502691896258f * bp       // sqrt(1/3)
                 - 0.5f * hwS[h] * d2s
                 + maskn[k];
    }
    __syncthreads();

    // softmax over k per head (wave-parallel, lanes 0..49 hold values)
    for (int h = wid; h < HH; h += 4) {
        float v = (lane < KNB) ? aP[h][lane] : -1e30f;
        float mx = v;
        #pragma unroll
        for (int off = 32; off; off >>= 1) mx = fmaxf(mx, __shfl_xor(mx, off));
        float e = (lane < KNB) ? expf(v - mx) : 0.f;
        float s = e;
        #pragma unroll
        for (int off = 32; off; off >>= 1) s += __shfl_xor(s, off);
        if (lane < KNB) aP[h][lane] = e / s;
    }
    __syncthreads();

    // o (48 float4) and o_pt raw (72 float4)
    if (tid < 120) {
        float4 acc = {0.f, 0.f, 0.f, 0.f};
        if (tid < 48) {
            int h = tid >> 2, c4 = tid & 3;
            for (int k = 0; k < KNB; ++k) {
                int mk = b * NN + nk[k];
                float4 v4 = *(const float4*)(lin + (size_t)mk * LINW + 192 + h*32 + 16 + c4*4);
                float a = aP[h][k];
                acc.x += a*v4.x; acc.y += a*v4.y; acc.z += a*v4.z; acc.w += a*v4.w;
            }
            us4 o = { f2b(acc.x), f2b(acc.y), f2b(acc.z), f2b(acc.w) };
            *(us4*)(cat + (size_t)m * CATW + tid * 4) = o;
        } else {
            int u2 = tid - 48;                   // 0..71
            int h = (u2 * 4) / 24, r = (u2 * 4) % 24;
            for (int k = 0; k < KNB; ++k) {
                int mk = b * NN + nk[k];
                float4 v4 = *(const float4*)(v_pts + (size_t)mk * 288 + h*24 + r);
                float a = aP[h][k];
                acc.x += a*v4.x; acc.y += a*v4.y; acc.z += a*v4.z; acc.w += a*v4.w;
            }
            *(float4*)&opt[u2 * 4] = acc;
        }
    }
    __syncthreads();

    // inverse frame transform + norm
    if (tid < 96) {
        int hp = tid;
        float x = opt[hp*3+0] - trans[(size_t)m*3+0];
        float y = opt[hp*3+1] - trans[(size_t)m*3+1];
        float z0 = opt[hp*3+2] - trans[(size_t)m*3+2];
        const float* R = rot + (size_t)m * 9;
        float o0 = R[0]*x + R[3]*y + R[6]*z0;   // rot^T
        float o1 = R[1]*x + R[4]*y + R[7]*z0;
        float o2 = R[2]*x + R[5]*y + R[8]*z0;
        float nrm = sqrtf(o0*o0 + o1*o1 + o2*o2 + 1e-8f);
        unsigned short* c0 = cat + (size_t)m * CATW;
        c0[192 + hp] = f2b(o0);
        c0[288 + hp] = f2b(o1);
        c0[384 + hp] = f2b(o2);
        c0[480 + hp] = f2b(nrm);
    }

    // o_pair: 12 heads x 32 float4 columns from LDS zn
    for (int u = tid; u < HH * 32; u += 256) {
        int h = u >> 5, c4 = u & 31;
        float4 acc = {0.f, 0.f, 0.f, 0.f};
        for (int k = 0; k < KNB; ++k) {
            float a = aP[h][k];
            float4 z4 = *(const float4*)&zn[k][c4 * 4];
            acc.x += a*z4.x; acc.y += a*z4.y; acc.z += a*z4.z; acc.w += a*z4.w;
        }
        us4 o = { f2b(acc.x), f2b(acc.y), f2b(acc.z), f2b(acc.w) };
        *(us4*)(cat + (size_t)m * CATW + 576 + h * 128 + c4 * 4) = o;
    }
}

extern "C" void kernel_launch(void* const* d_in, const int* in_sizes, int n_in,
                              void* d_out, int out_size, void* d_ws, size_t ws_size,
                              hipStream_t stream) {
    const float* s     = (const float*)d_in[0];
    const float* z     = (const float*)d_in[1];
    const float* rot   = (const float*)d_in[2];
    const float* trans = (const float*)d_in[3];
    const float* mask  = (const float*)d_in[4];
    // d_in[5] rel_pos unused
    const float* Wq    = (const float*)d_in[6];
    const float* bq    = (const float*)d_in[7];
    const float* Wkv   = (const float*)d_in[8];
    const float* bkv   = (const float*)d_in[9];
    const float* Wqp   = (const float*)d_in[10];
    const float* bqp   = (const float*)d_in[11];
    const float* Wkvp  = (const float*)d_in[12];
    const float* bkvp  = (const float*)d_in[13];
    const float* Wb    = (const float*)d_in[14];
    const float* bb    = (const float*)d_in[15];
    const float* hw    = (const float*)d_in[16];
    const float* Wout  = (const float*)d_in[17];
    const float* bout  = (const float*)d_in[18];
    float* out = (float*)d_out;

    float* ws    = (float*)d_ws;
    float* lin   = ws;                              // 2048*1152 f32
    float* qpts  = lin  + (size_t)MTOK * LINW;      // 2048*144
    float* kpts  = qpts + (size_t)MTOK * 144;       // 2048*144
    float* vpts  = kpts + (size_t)MTOK * 144;       // 2048*288
    int*   nidxb = (int*)(vpts + (size_t)MTOK * 288);
    unsigned short* catb = (unsigned short*)(nidxb + (size_t)MTOK * KNB); // 2048*2112 bf16
    unsigned short* wob  = catb + (size_t)MTOK * CATW;                    // 384*2112 bf16
    float* parts = (float*)(wob + (size_t)384 * CATW);                    // OSK*2048*384 f32

    convert_wout<<<(384 * CATW / 4 + 255) / 256, 256, 0, stream>>>(Wout, wob);
    dim3 g1(MTOK / 64, LINW / 64);
    proj_gemm<<<g1, 256, 0, stream>>>(s, Wq, bq, Wkv, bkv, Wqp, bqp, Wkvp, bkvp, lin);
    point_transform<<<MTOK, 192, 0, stream>>>(lin, rot, trans, qpts, kpts, vpts);
    topk_kernel<<<MTOK, 256, 0, stream>>>(trans, nidxb);
    attn_kernel<<<MTOK, 256, 0, stream>>>(lin, qpts, kpts, vpts, nidxb, z, Wb, bb, hw,
                                          mask, rot, trans, catb);
    dim3 g2(MTOK / 128, 384 / 64, OSK);
    gemm_out_mfma<<<g2, 256, 0, stream>>>(catb, wob, parts);
    reduce_splitk<<<(MTOK * 384 / 4 + 255) / 256, 256, 0, stream>>>(parts, bout, out);
}

// Round 7
// 140.006 us; speedup vs baseline: 1.8083x; 1.1572x over previous
//
#include <hip/hip_runtime.h>
#include <math.h>

#define BB    2
#define NN    1024
#define CSD   384
#define CZD   128
#define CZP   132     // padded LDS row (bank spread)
#define CHD   16
#define HH    12
#define PQD   4
#define PVD   8
#define KNB   50
#define HALFN 512
#define MTOK  (BB*NN)
#define LINW  1152
#define CATW  2112
#define OSK   3       // split-K for bf16 out-GEMM
#define OKSTEP (CATW / OSK)   // 704

typedef __attribute__((ext_vector_type(8))) short    bf16x8;
typedef __attribute__((ext_vector_type(4))) float    f32x4;
typedef __attribute__((ext_vector_type(4))) unsigned short us4;

// fp32 -> bf16 round-to-nearest-even (finite inputs; no header dependency)
static __device__ __forceinline__ unsigned short f2b(float x) {
    unsigned u = __float_as_uint(x);
    unsigned rnd = 0x7fffu + ((u >> 16) & 1u);
    return (unsigned short)((u + rnd) >> 16);
}

// ------------- one-pass fp32 -> bf16 conversions: s, packed proj W, Wout -------------
#define CV_N0 (MTOK * CSD / 4)        // s
#define CV_N1 (LINW * CSD / 4)        // packed proj weights
#define CV_N2 (384 * CATW / 4)        // Wout
__global__ __launch_bounds__(256) void convert_all(
    const float* __restrict__ s,
    const float* __restrict__ Wq,  const float* __restrict__ Wkv,
    const float* __restrict__ Wqp, const float* __restrict__ Wkvp,
    const float* __restrict__ Wout,
    unsigned short* __restrict__ sb,
    unsigned short* __restrict__ wpb,
    unsigned short* __restrict__ wob)
{
    const int i4 = blockIdx.x * 256 + threadIdx.x;
    if (i4 < CV_N0) {
        float4 v = *(const float4*)(s + (size_t)i4 * 4);
        us4 o = { f2b(v.x), f2b(v.y), f2b(v.z), f2b(v.w) };
        *(us4*)(sb + (size_t)i4 * 4) = o;
    } else if (i4 < CV_N0 + CV_N1) {
        int j4 = i4 - CV_N0;
        int r = j4 / (CSD / 4), c4 = j4 % (CSD / 4);
        const float* W; int wr;
        if      (r < 192) { W = Wq;   wr = r;       }
        else if (r < 576) { W = Wkv;  wr = r - 192; }
        else if (r < 720) { W = Wqp;  wr = r - 576; }
        else              { W = Wkvp; wr = r - 720; }
        float4 v = *(const float4*)(W + (size_t)wr * CSD + c4 * 4);
        us4 o = { f2b(v.x), f2b(v.y), f2b(v.z), f2b(v.w) };
        *(us4*)(wpb + (size_t)r * CSD + c4 * 4) = o;
    } else if (i4 < CV_N0 + CV_N1 + CV_N2) {
        int j4 = i4 - CV_N0 - CV_N1;
        float4 v = *(const float4*)(Wout + (size_t)j4 * 4);
        us4 o = { f2b(v.x), f2b(v.y), f2b(v.z), f2b(v.w) };
        *(us4*)(wob + (size_t)j4 * 4) = o;
    }
}

// ------------- bf16 MFMA projection GEMM: lin = sb @ wpb^T + bias (f32 out) -------------
// 128x64 tile, 4 waves (2x2), each wave 64x32 via 4x2 fragments of 16x16x32.
__global__ __launch_bounds__(256) void gemm_proj_mfma(
    const unsigned short* __restrict__ sb,     // (2048, 384) bf16
    const unsigned short* __restrict__ wpb,    // (1152, 384) bf16
    const float* __restrict__ bq,  const float* __restrict__ bkv,
    const float* __restrict__ bqp, const float* __restrict__ bkvp,
    float* __restrict__ lin)                   // (2048, 1152) f32
{
    __shared__ unsigned short As[128][40];
    __shared__ unsigned short Bs[64][40];
    const int tid = threadIdx.x;
    const int lane = tid & 63, wv = tid >> 6;
    const int wr = wv >> 1, wc = wv & 1;
    const int rowBase = blockIdx.x * 128;
    const int colBase = blockIdx.y * 64;
    const int sr = tid >> 2;
    const int sq = (tid & 3) * 8;
    const unsigned short* aRow0 = sb  + (size_t)(rowBase + sr) * CSD + sq;
    const unsigned short* aRow1 = sb  + (size_t)(rowBase + 64 + sr) * CSD + sq;
    const unsigned short* bRow  = wpb + (size_t)(colBase + sr) * CSD + sq;

    f32x4 acc[4][2];
    #pragma unroll
    for (int i = 0; i < 4; ++i)
        #pragma unroll
        for (int j = 0; j < 2; ++j)
            acc[i][j] = (f32x4){0.f, 0.f, 0.f, 0.f};

    const int kg = (lane >> 4) * 8;
    const int rr = lane & 15;

    for (int k0 = 0; k0 < CSD; k0 += 32) {
        bf16x8 a0 = *(const bf16x8*)(aRow0 + k0);
        bf16x8 a1 = *(const bf16x8*)(aRow1 + k0);
        bf16x8 b0 = *(const bf16x8*)(bRow  + k0);
        __syncthreads();
        *(bf16x8*)&As[sr][sq]      = a0;
        *(bf16x8*)&As[64 + sr][sq] = a1;
        *(bf16x8*)&Bs[sr][sq]      = b0;
        __syncthreads();
        bf16x8 bfr[2], afr[4];
        #pragma unroll
        for (int fc = 0; fc < 2; ++fc)
            bfr[fc] = *(const bf16x8*)&Bs[wc*32 + fc*16 + rr][kg];
        #pragma unroll
        for (int fr = 0; fr < 4; ++fr)
            afr[fr] = *(const bf16x8*)&As[wr*64 + fr*16 + rr][kg];
        #pragma unroll
        for (int fr = 0; fr < 4; ++fr)
            #pragma unroll
            for (int fc = 0; fc < 2; ++fc)
                acc[fr][fc] = __builtin_amdgcn_mfma_f32_16x16x32_bf16(
                    afr[fr], bfr[fc], acc[fr][fc], 0, 0, 0);
    }

    const int cRowL = (lane >> 4) * 4;
    const int cColL = lane & 15;
    #pragma unroll
    for (int fc = 0; fc < 2; ++fc) {
        int col = colBase + wc*32 + fc*16 + cColL;
        float bia;
        if      (col < 192) bia = bq[col];
        else if (col < 576) bia = bkv[col - 192];
        else if (col < 720) bia = bqp[col - 576];
        else                bia = bkvp[col - 720];
        #pragma unroll
        for (int fr = 0; fr < 4; ++fr) {
            int row0 = rowBase + wr*64 + fr*16 + cRowL;
            #pragma unroll
            for (int g = 0; g < 4; ++g)
                lin[(size_t)(row0 + g) * LINW + col] = acc[fr][fc][g] + bia;
        }
    }
}

// ------------- bf16 MFMA out-GEMM: parts[z] = catb @ wob^T over k-chunk -------------
__global__ __launch_bounds__(256) void gemm_out_mfma(
    const unsigned short* __restrict__ catb,   // (2048, 2112) bf16
    const unsigned short* __restrict__ wob,    // (384, 2112) bf16
    float* __restrict__ parts)
{
    __shared__ unsigned short As[128][40];
    __shared__ unsigned short Bs[64][40];
    const int tid = threadIdx.x;
    const int lane = tid & 63, wv = tid >> 6;
    const int wr = wv >> 1, wc = wv & 1;
    const int rowBase = blockIdx.x * 128;
    const int colBase = blockIdx.y * 64;
    const int k0s = blockIdx.z * OKSTEP;
    const int sr = tid >> 2;
    const int sq = (tid & 3) * 8;
    const unsigned short* aRow0 = catb + (size_t)(rowBase + sr) * CATW + k0s + sq;
    const unsigned short* aRow1 = catb + (size_t)(rowBase + 64 + sr) * CATW + k0s + sq;
    const unsigned short* bRow  = wob  + (size_t)(colBase + sr) * CATW + k0s + sq;

    f32x4 acc[4][2];
    #pragma unroll
    for (int i = 0; i < 4; ++i)
        #pragma unroll
        for (int j = 0; j < 2; ++j)
            acc[i][j] = (f32x4){0.f, 0.f, 0.f, 0.f};

    const int kg = (lane >> 4) * 8;
    const int rr = lane & 15;

    for (int k0 = 0; k0 < OKSTEP; k0 += 32) {
        bf16x8 a0 = *(const bf16x8*)(aRow0 + k0);
        bf16x8 a1 = *(const bf16x8*)(aRow1 + k0);
        bf16x8 b0 = *(const bf16x8*)(bRow  + k0);
        __syncthreads();
        *(bf16x8*)&As[sr][sq]      = a0;
        *(bf16x8*)&As[64 + sr][sq] = a1;
        *(bf16x8*)&Bs[sr][sq]      = b0;
        __syncthreads();
        bf16x8 bfr[2], afr[4];
        #pragma unroll
        for (int fc = 0; fc < 2; ++fc)
            bfr[fc] = *(const bf16x8*)&Bs[wc*32 + fc*16 + rr][kg];
        #pragma unroll
        for (int fr = 0; fr < 4; ++fr)
            afr[fr] = *(const bf16x8*)&As[wr*64 + fr*16 + rr][kg];
        #pragma unroll
        for (int fr = 0; fr < 4; ++fr)
            #pragma unroll
            for (int fc = 0; fc < 2; ++fc)
                acc[fr][fc] = __builtin_amdgcn_mfma_f32_16x16x32_bf16(
                    afr[fr], bfr[fc], acc[fr][fc], 0, 0, 0);
    }

    float* dst = parts + (size_t)blockIdx.z * MTOK * 384;
    const int cRowL = (lane >> 4) * 4;
    const int cColL = lane & 15;
    #pragma unroll
    for (int fr = 0; fr < 4; ++fr) {
        #pragma unroll
        for (int fc = 0; fc < 2; ++fc) {
            int col = colBase + wc*32 + fc*16 + cColL;
            int row0 = rowBase + wr*64 + fr*16 + cRowL;
            #pragma unroll
            for (int g = 0; g < 4; ++g)
                dst[(size_t)(row0 + g) * 384 + col] = acc[fr][fc][g];
        }
    }
}

__global__ __launch_bounds__(256) void reduce_splitk(
    const float* __restrict__ parts, const float* __restrict__ bias,
    float* __restrict__ out)
{
    const int i4 = blockIdx.x * 256 + threadIdx.x;   // float4 index
    const int TOT4 = MTOK * 384 / 4;
    if (i4 >= TOT4) return;
    const int c4 = i4 % (384 / 4);
    float4 acc = *(const float4*)(bias + c4 * 4);
    #pragma unroll
    for (int s = 0; s < OSK; ++s) {
        float4 p = *(const float4*)(parts + (size_t)s * MTOK * 384 + (size_t)i4 * 4);
        acc.x += p.x; acc.y += p.y; acc.z += p.z; acc.w += p.w;
    }
    *(float4*)(out + (size_t)i4 * 4) = acc;
}

// ------------- point transform: rot @ p + trans -------------
__global__ void point_transform(const float* __restrict__ lin,
                                const float* __restrict__ rot,
                                const float* __restrict__ trans,
                                float* __restrict__ q_pts,
                                float* __restrict__ k_pts,
                                float* __restrict__ v_pts)
{
    const int m = blockIdx.x;
    const int j = threadIdx.x;   // 0..191
    const float* R = rot + (size_t)m * 9;
    const float* T = trans + (size_t)m * 3;
    const float* L = lin + (size_t)m * LINW;
    float p0, p1, p2;
    if (j < 48) {
        p0 = L[576 + j]; p1 = L[576 + 48 + j]; p2 = L[576 + 96 + j];
    } else {
        int j2 = j - 48;                     // 0..143
        p0 = L[720 + j2]; p1 = L[720 + 144 + j2]; p2 = L[720 + 288 + j2];
    }
    float ox = R[0]*p0 + R[1]*p1 + R[2]*p2 + T[0];
    float oy = R[3]*p0 + R[4]*p1 + R[5]*p2 + T[1];
    float oz = R[6]*p0 + R[7]*p1 + R[8]*p2 + T[2];
    if (j < 48) {
        float* o = q_pts + (size_t)m * 144 + 3 * j;
        o[0] = ox; o[1] = oy; o[2] = oz;
    } else {
        int j2 = j - 48, h = j2 / 12, pp = j2 % 12;
        if (pp < PQD) {
            float* o = k_pts + (size_t)m * 144 + ((h*PQD + pp) * 3);
            o[0] = ox; o[1] = oy; o[2] = oz;
        } else {
            float* o = v_pts + (size_t)m * 288 + ((h*PVD + pp - PQD) * 3);
            o[0] = ox; o[1] = oy; o[2] = oz;
        }
    }
}

// ------------- top-K neighbors via radix-select (d^2 key; per-wave sub-hists) -------------
__global__ __launch_bounds__(256) void topk_kernel(const float* __restrict__ trans,
                                                   int* __restrict__ nidx)
{
    __shared__ float t3[3 * NN];
    __shared__ unsigned long long keys[NN];
    __shared__ unsigned int hist[4][256];
    __shared__ unsigned int warp_sums[4];
    __shared__ unsigned int s_seldig, s_selexc, s_selcnt, out_cnt;
    __shared__ unsigned long long s_pivot;
    __shared__ int s_done;

    const int m = blockIdx.x, b = m / NN, n = m % NN, tid = threadIdx.x;
    const int lane = tid & 63, wid = tid >> 6;

    if (tid == 0) { s_done = 0; out_cnt = 0; }
    for (int i = tid; i < 3 * NN; i += 256) t3[i] = trans[(size_t)b * 3 * NN + i];
    __syncthreads();
    const float tx = t3[n*3], ty = t3[n*3+1], tz = t3[n*3+2];
    for (int j = tid; j < NN; j += 256) {
        float dx = tx - t3[j*3], dy = ty - t3[j*3+1], dz = tz - t3[j*3+2];
        float d = dx*dx + dy*dy + dz*dz;          // rank-equivalent to sqrt
        keys[j] = ((unsigned long long)__float_as_uint(d) << 32) | (unsigned)j;
    }

    unsigned long long hi = 0;
    int rank = 0;
    const int target = KNB - 1;
    for (int d = 7; d >= 0; --d) {
        __syncthreads();
        if (s_done) break;
        const int shift = d * 8;
        for (int i = tid; i < 1024; i += 256) ((unsigned int*)hist)[i] = 0;
        __syncthreads();
        for (int j = tid; j < NN; j += 256) {
            unsigned long long key = keys[j];
            bool match = (d == 7) || ((key >> (shift + 8)) == hi);
            if (match) atomicAdd(&hist[wid][(unsigned)(key >> shift) & 0xffu], 1u);
        }
        __syncthreads();
        unsigned int v = hist[0][tid] + hist[1][tid] + hist[2][tid] + hist[3][tid];
        unsigned int inc = v;
        #pragma unroll
        for (int off = 1; off < 64; off <<= 1) {
            unsigned int nv = __shfl_up(inc, off);
            if (lane >= off) inc += nv;
        }
        if (lane == 63) warp_sums[wid] = inc;
        __syncthreads();
        unsigned int woff = 0;
        for (int w = 0; w < wid; ++w) woff += warp_sums[w];
        unsigned int exc = woff + inc - v;
        int t = target - rank;
        if ((int)exc <= t && t < (int)(exc + v)) {
            s_seldig = (unsigned)tid; s_selexc = exc; s_selcnt = v;
        }
        __syncthreads();
        hi = (hi << 8) | (unsigned long long)s_seldig;
        rank += (int)s_selexc;
        if (s_selcnt == 1u) {
            for (int j = tid; j < NN; j += 256) {
                unsigned long long key = keys[j];
                if ((key >> shift) == hi) s_pivot = key;
            }
            if (tid == 0) s_done = 1;
        } else if (d == 0) {
            if (tid == 0) { s_pivot = hi; s_done = 1; }
        }
    }
    __syncthreads();
    const unsigned long long pivot = s_pivot;
    for (int j = tid; j < NN; j += 256) {
        unsigned long long key = keys[j];
        if (key <= pivot) {
            unsigned p = atomicAdd(&out_cnt, 1u);
            nidx[(size_t)m * KNB + p] = (int)(key & 0xffffffffu);
        }
    }
}

// ------------- attention per token (writes cat in bf16) -------------
__global__ __launch_bounds__(256) void attn_kernel(
    const float* __restrict__ lin,     // q at +0, kv at +192 (per 1152-row)
    const float* __restrict__ q_pts,
    const float* __restrict__ k_pts,
    const float* __restrict__ v_pts,
    const int*   __restrict__ nidx,
    const float* __restrict__ z,       // (B, 512, 512, 128)
    const float* __restrict__ Wb,      // (12, 128)
    const float* __restrict__ bbv,     // (12)
    const float* __restrict__ hwin,    // (12)
    const float* __restrict__ mask,    // (B, N)
    const float* __restrict__ rot,
    const float* __restrict__ trans,
    unsigned short* __restrict__ cat)  // (M, 2112) bf16
{
    __shared__ __align__(16) float zn[KNB][CZP];     // 26.4 KB, padded rows
    __shared__ __align__(16) float WbS[HH][CZP];     // 6.3 KB
    __shared__ float aP[HH][KNB + 2];
    __shared__ __align__(16) float qloc[192];
    __shared__ __align__(16) float qp[144];
    __shared__ int   nk[KNB];
    __shared__ float maskn[KNB];
    __shared__ float hwS[HH];
    __shared__ __align__(16) float opt[288];

    const int m = blockIdx.x;
    const int b = m / NN, n = m % NN;
    const int tid = threadIdx.x;
    const int lane = tid & 63, wid = tid >> 6;

    if (tid < KNB) nk[tid] = nidx[(size_t)m * KNB + tid];
    __syncthreads();

    for (int i = tid; i < HH * CZD; i += 256) WbS[i / CZD][i % CZD] = Wb[i];
    for (int i = tid; i < 192; i += 256) qloc[i] = lin[(size_t)m * LINW + i];
    for (int i = tid; i < 144; i += 256) qp[i] = q_pts[(size_t)m * 144 + i];
    if (tid < HH) hwS[tid] = log1pf(expf(hwin[tid])) * 0.13608276348795434f; // sqrt(1/54)
    if (tid < KNB) maskn[tid] = 100000.0f * (mask[m] * mask[(size_t)b * NN + nk[tid]] - 1.0f);
    {
        const int sub = lane >> 5, l32 = lane & 31;
        for (int k = wid * 2 + sub; k < KNB; k += 8) {
            const float* zr = z + (((size_t)b * HALFN + (n & (HALFN-1))) * HALFN + (nk[k] & (HALFN-1))) * CZD;
            float4 v4 = *(const float4*)(zr + l32 * 4);
            *(float4*)&zn[k][l32 * 4] = v4;
        }
    }
    __syncthreads();

    // logits
    for (int idx = tid; idx < HH * KNB; idx += 256) {
        int k = idx / HH, h = idx % HH;
        int mk = b * NN + nk[k];
        const float* kvr = lin + (size_t)mk * LINW + 192 + h * 32;
        float qk = 0.f;
        #pragma unroll
        for (int c4 = 0; c4 < 4; ++c4) {
            float4 kv4 = *(const float4*)(kvr + c4 * 4);
            float4 q4  = *(const float4*)&qloc[h * 16 + c4 * 4];
            qk += q4.x*kv4.x + q4.y*kv4.y + q4.z*kv4.z + q4.w*kv4.w;
        }
        const float* kpr = k_pts + (size_t)mk * 144 + h * 12;
        float kp[12], qv[12];
        *(float4*)&kp[0] = *(const float4*)(kpr);
        *(float4*)&kp[4] = *(const float4*)(kpr + 4);
        *(float4*)&kp[8] = *(const float4*)(kpr + 8);
        *(float4*)&qv[0] = *(const float4*)&qp[h*12];
        *(float4*)&qv[4] = *(const float4*)&qp[h*12 + 4];
        *(float4*)&qv[8] = *(const float4*)&qp[h*12 + 8];
        float d2s = 0.f;
        #pragma unroll
        for (int e = 0; e < 12; ++e) { float dd = qv[e] - kp[e]; d2s += dd*dd; }
        float4 acc4 = {0.f, 0.f, 0.f, 0.f};
        #pragma unroll 8
        for (int c4 = 0; c4 < 32; ++c4) {
            float4 z4 = *(const float4*)&zn[k][c4 * 4];
            float4 w4 = *(const float4*)&WbS[h][c4 * 4];
            acc4.x += z4.x*w4.x; acc4.y += z4.y*w4.y;
            acc4.z += z4.z*w4.z; acc4.w += z4.w*w4.w;
        }
        float bp = bbv[h] + acc4.x + acc4.y + acc4.z + acc4.w;
        aP[h][k] = qk * 0.14433756729740643f      // sqrt(1/(3*16))
                 + 0.5773502691896258f * bp       // sqrt(1/3)
                 - 0.5f * hwS[h] * d2s
                 + maskn[k];
    }
    __syncthreads();

    // softmax over k per head (wave-parallel, lanes 0..49 hold values)
    for (int h = wid; h < HH; h += 4) {
        float v = (lane < KNB) ? aP[h][lane] : -1e30f;
        float mx = v;
        #pragma unroll
        for (int off = 32; off; off >>= 1) mx = fmaxf(mx, __shfl_xor(mx, off));
        float e = (lane < KNB) ? expf(v - mx) : 0.f;
        float s = e;
        #pragma unroll
        for (int off = 32; off; off >>= 1) s += __shfl_xor(s, off);
        if (lane < KNB) aP[h][lane] = e / s;
    }
    __syncthreads();

    // o (48 float4) and o_pt raw (72 float4)
    if (tid < 120) {
        float4 acc = {0.f, 0.f, 0.f, 0.f};
        if (tid < 48) {
            int h = tid >> 2, c4 = tid & 3;
            for (int k = 0; k < KNB; ++k) {
                int mk = b * NN + nk[k];
                float4 v4 = *(const float4*)(lin + (size_t)mk * LINW + 192 + h*32 + 16 + c4*4);
                float a = aP[h][k];
                acc.x += a*v4.x; acc.y += a*v4.y; acc.z += a*v4.z; acc.w += a*v4.w;
            }
            us4 o = { f2b(acc.x), f2b(acc.y), f2b(acc.z), f2b(acc.w) };
            *(us4*)(cat + (size_t)m * CATW + tid * 4) = o;
        } else {
            int u2 = tid - 48;                   // 0..71
            int h = (u2 * 4) / 24, r = (u2 * 4) % 24;
            for (int k = 0; k < KNB; ++k) {
                int mk = b * NN + nk[k];
                float4 v4 = *(const float4*)(v_pts + (size_t)mk * 288 + h*24 + r);
                float a = aP[h][k];
                acc.x += a*v4.x; acc.y += a*v4.y; acc.z += a*v4.z; acc.w += a*v4.w;
            }
            *(float4*)&opt[u2 * 4] = acc;
        }
    }
    __syncthreads();

    // inverse frame transform + norm
    if (tid < 96) {
        int hp = tid;
        float x = opt[hp*3+0] - trans[(size_t)m*3+0];
        float y = opt[hp*3+1] - trans[(size_t)m*3+1];
        float z0 = opt[hp*3+2] - trans[(size_t)m*3+2];
        const float* R = rot + (size_t)m * 9;
        float o0 = R[0]*x + R[3]*y + R[6]*z0;   // rot^T
        float o1 = R[1]*x + R[4]*y + R[7]*z0;
        float o2 = R[2]*x + R[5]*y + R[8]*z0;
        float nrm = sqrtf(o0*o0 + o1*o1 + o2*o2 + 1e-8f);
        unsigned short* c0 = cat + (size_t)m * CATW;
        c0[192 + hp] = f2b(o0);
        c0[288 + hp] = f2b(o1);
        c0[384 + hp] = f2b(o2);
        c0[480 + hp] = f2b(nrm);
    }

    // o_pair: 12 heads x 32 float4 columns from LDS zn
    for (int u = tid; u < HH * 32; u += 256) {
        int h = u >> 5, c4 = u & 31;
        float4 acc = {0.f, 0.f, 0.f, 0.f};
        for (int k = 0; k < KNB; ++k) {
            float a = aP[h][k];
            float4 z4 = *(const float4*)&zn[k][c4 * 4];
            acc.x += a*z4.x; acc.y += a*z4.y; acc.z += a*z4.z; acc.w += a*z4.w;
        }
        us4 o = { f2b(acc.x), f2b(acc.y), f2b(acc.z), f2b(acc.w) };
        *(us4*)(cat + (size_t)m * CATW + 576 + h * 128 + c4 * 4) = o;
    }
}

extern "C" void kernel_launch(void* const* d_in, const int* in_sizes, int n_in,
                              void* d_out, int out_size, void* d_ws, size_t ws_size,
                              hipStream_t stream) {
    const float* s     = (const float*)d_in[0];
    const float* z     = (const float*)d_in[1];
    const float* rot   = (const float*)d_in[2];
    const float* trans = (const float*)d_in[3];
    const float* mask  = (const float*)d_in[4];
    // d_in[5] rel_pos unused
    const float* Wq    = (const float*)d_in[6];
    const float* bq    = (const float*)d_in[7];
    const float* Wkv   = (const float*)d_in[8];
    const float* bkv   = (const float*)d_in[9];
    const float* Wqp   = (const float*)d_in[10];
    const float* bqp   = (const float*)d_in[11];
    const float* Wkvp  = (const float*)d_in[12];
    const float* bkvp  = (const float*)d_in[13];
    const float* Wb    = (const float*)d_in[14];
    const float* bb    = (const float*)d_in[15];
    const float* hw    = (const float*)d_in[16];
    const float* Wout  = (const float*)d_in[17];
    const float* bout  = (const float*)d_in[18];
    float* out = (float*)d_out;

    float* ws    = (float*)d_ws;
    float* lin   = ws;                              // 2048*1152 f32
    float* qpts  = lin  + (size_t)MTOK * LINW;      // 2048*144
    float* kpts  = qpts + (size_t)MTOK * 144;       // 2048*144
    float* vpts  = kpts + (size_t)MTOK * 144;       // 2048*288
    int*   nidxb = (int*)(vpts + (size_t)MTOK * 288);
    unsigned short* catb = (unsigned short*)(nidxb + (size_t)MTOK * KNB); // 2048*2112 bf16
    unsigned short* wob  = catb + (size_t)MTOK * CATW;                    // 384*2112 bf16
    unsigned short* sb   = wob  + (size_t)384 * CATW;                     // 2048*384 bf16
    unsigned short* wpb  = sb   + (size_t)MTOK * CSD;                     // 1152*384 bf16
    float* parts = (float*)(wpb + (size_t)LINW * CSD);                    // OSK*2048*384 f32

    const int CV_TOT = CV_N0 + CV_N1 + CV_N2;
    convert_all<<<(CV_TOT + 255) / 256, 256, 0, stream>>>(s, Wq, Wkv, Wqp, Wkvp, Wout,
                                                          sb, wpb, wob);
    dim3 g1(MTOK / 128, LINW / 64);
    gemm_proj_mfma<<<g1, 256, 0, stream>>>(sb, wpb, bq, bkv, bqp, bkvp, lin);
    point_transform<<<MTOK, 192, 0, stream>>>(lin, rot, trans, qpts, kpts, vpts);
    topk_kernel<<<MTOK, 256, 0, stream>>>(trans, nidxb);
    attn_kernel<<<MTOK, 256, 0, stream>>>(lin, qpts, kpts, vpts, nidxb, z, Wb, bb, hw,
                                          mask, rot, trans, catb);
    dim3 g2(MTOK / 128, 384 / 64, OSK);
    gemm_out_mfma<<<g2, 256, 0, stream>>>(catb, wob, parts);
    reduce_splitk<<<(MTOK * 384 / 4 + 255) / 256, 256, 0, stream>>>(parts, bout, out);
}

// Round 9
// 137.487 us; speedup vs baseline: 1.8414x; 1.0183x over previous
//
#include <hip/hip_runtime.h>
#include <math.h>

#define BB    2
#define NN    1024
#define CSD   384
#define CZD   128
#define CZP   132     // padded LDS row (bank spread)
#define CHD   16
#define HH    12
#define PQD   4
#define PVD   8
#define KNB   50
#define HALFN 512
#define MTOK  (BB*NN)
#define LINW  1152
#define CATW  2112
#define OSK   6       // split-K for bf16 out-GEMM
#define OKSTEP (CATW / OSK)   // 352 = 11*32

typedef __attribute__((ext_vector_type(8))) short    bf16x8;
typedef __attribute__((ext_vector_type(4))) float    f32x4;
typedef __attribute__((ext_vector_type(4))) unsigned short us4;

// fp32 -> bf16 round-to-nearest-even (finite inputs; no header dependency)
static __device__ __forceinline__ unsigned short f2b(float x) {
    unsigned u = __float_as_uint(x);
    unsigned rnd = 0x7fffu + ((u >> 16) & 1u);
    return (unsigned short)((u + rnd) >> 16);
}

// ------------- one-pass fp32 -> bf16 conversions: s, packed proj W, Wout -------------
#define CV_N0 (MTOK * CSD / 4)        // s
#define CV_N1 (LINW * CSD / 4)        // packed proj weights
#define CV_N2 (384 * CATW / 4)        // Wout
__global__ __launch_bounds__(256) void convert_all(
    const float* __restrict__ s,
    const float* __restrict__ Wq,  const float* __restrict__ Wkv,
    const float* __restrict__ Wqp, const float* __restrict__ Wkvp,
    const float* __restrict__ Wout,
    unsigned short* __restrict__ sb,
    unsigned short* __restrict__ wpb,
    unsigned short* __restrict__ wob)
{
    const int i4 = blockIdx.x * 256 + threadIdx.x;
    if (i4 < CV_N0) {
        float4 v = *(const float4*)(s + (size_t)i4 * 4);
        us4 o = { f2b(v.x), f2b(v.y), f2b(v.z), f2b(v.w) };
        *(us4*)(sb + (size_t)i4 * 4) = o;
    } else if (i4 < CV_N0 + CV_N1) {
        int j4 = i4 - CV_N0;
        int r = j4 / (CSD / 4), c4 = j4 % (CSD / 4);
        const float* W; int wr;
        if      (r < 192) { W = Wq;   wr = r;       }
        else if (r < 576) { W = Wkv;  wr = r - 192; }
        else if (r < 720) { W = Wqp;  wr = r - 576; }
        else              { W = Wkvp; wr = r - 720; }
        float4 v = *(const float4*)(W + (size_t)wr * CSD + c4 * 4);
        us4 o = { f2b(v.x), f2b(v.y), f2b(v.z), f2b(v.w) };
        *(us4*)(wpb + (size_t)r * CSD + c4 * 4) = o;
    } else if (i4 < CV_N0 + CV_N1 + CV_N2) {
        int j4 = i4 - CV_N0 - CV_N1;
        float4 v = *(const float4*)(Wout + (size_t)j4 * 4);
        us4 o = { f2b(v.x), f2b(v.y), f2b(v.z), f2b(v.w) };
        *(us4*)(wob + (size_t)j4 * 4) = o;
    }
}

// ------------- bf16 MFMA projection GEMM: lin = sb @ wpb^T + bias (f32 out) -------------
__global__ __launch_bounds__(256) void gemm_proj_mfma(
    const unsigned short* __restrict__ sb,     // (2048, 384) bf16
    const unsigned short* __restrict__ wpb,    // (1152, 384) bf16
    const float* __restrict__ bq,  const float* __restrict__ bkv,
    const float* __restrict__ bqp, const float* __restrict__ bkvp,
    float* __restrict__ lin)                   // (2048, 1152) f32
{
    __shared__ unsigned short As[128][40];
    __shared__ unsigned short Bs[64][40];
    const int tid = threadIdx.x;
    const int lane = tid & 63, wv = tid >> 6;
    const int wr = wv >> 1, wc = wv & 1;
    const int rowBase = blockIdx.x * 128;
    const int colBase = blockIdx.y * 64;
    const int sr = tid >> 2;
    const int sq = (tid & 3) * 8;
    const unsigned short* aRow0 = sb  + (size_t)(rowBase + sr) * CSD + sq;
    const unsigned short* aRow1 = sb  + (size_t)(rowBase + 64 + sr) * CSD + sq;
    const unsigned short* bRow  = wpb + (size_t)(colBase + sr) * CSD + sq;

    f32x4 acc[4][2];
    #pragma unroll
    for (int i = 0; i < 4; ++i)
        #pragma unroll
        for (int j = 0; j < 2; ++j)
            acc[i][j] = (f32x4){0.f, 0.f, 0.f, 0.f};

    const int kg = (lane >> 4) * 8;
    const int rr = lane & 15;

    for (int k0 = 0; k0 < CSD; k0 += 32) {
        bf16x8 a0 = *(const bf16x8*)(aRow0 + k0);
        bf16x8 a1 = *(const bf16x8*)(aRow1 + k0);
        bf16x8 b0 = *(const bf16x8*)(bRow  + k0);
        __syncthreads();
        *(bf16x8*)&As[sr][sq]      = a0;
        *(bf16x8*)&As[64 + sr][sq] = a1;
        *(bf16x8*)&Bs[sr][sq]      = b0;
        __syncthreads();
        bf16x8 bfr[2], afr[4];
        #pragma unroll
        for (int fc = 0; fc < 2; ++fc)
            bfr[fc] = *(const bf16x8*)&Bs[wc*32 + fc*16 + rr][kg];
        #pragma unroll
        for (int fr = 0; fr < 4; ++fr)
            afr[fr] = *(const bf16x8*)&As[wr*64 + fr*16 + rr][kg];
        #pragma unroll
        for (int fr = 0; fr < 4; ++fr)
            #pragma unroll
            for (int fc = 0; fc < 2; ++fc)
                acc[fr][fc] = __builtin_amdgcn_mfma_f32_16x16x32_bf16(
                    afr[fr], bfr[fc], acc[fr][fc], 0, 0, 0);
    }

    const int cRowL = (lane >> 4) * 4;
    const int cColL = lane & 15;
    #pragma unroll
    for (int fc = 0; fc < 2; ++fc) {
        int col = colBase + wc*32 + fc*16 + cColL;
        float bia;
        if      (col < 192) bia = bq[col];
        else if (col < 576) bia = bkv[col - 192];
        else if (col < 720) bia = bqp[col - 576];
        else                bia = bkvp[col - 720];
        #pragma unroll
        for (int fr = 0; fr < 4; ++fr) {
            int row0 = rowBase + wr*64 + fr*16 + cRowL;
            #pragma unroll
            for (int g = 0; g < 4; ++g)
                lin[(size_t)(row0 + g) * LINW + col] = acc[fr][fc][g] + bia;
        }
    }
}

// ------------- bf16 MFMA out-GEMM: parts[z] = catb @ wob^T over k-chunk -------------
__global__ __launch_bounds__(256) void gemm_out_mfma(
    const unsigned short* __restrict__ catb,   // (2048, 2112) bf16
    const unsigned short* __restrict__ wob,    // (384, 2112) bf16
    float* __restrict__ parts)
{
    __shared__ unsigned short As[128][40];
    __shared__ unsigned short Bs[64][40];
    const int tid = threadIdx.x;
    const int lane = tid & 63, wv = tid >> 6;
    const int wr = wv >> 1, wc = wv & 1;
    const int rowBase = blockIdx.x * 128;
    const int colBase = blockIdx.y * 64;
    const int k0s = blockIdx.z * OKSTEP;
    const int sr = tid >> 2;
    const int sq = (tid & 3) * 8;
    const unsigned short* aRow0 = catb + (size_t)(rowBase + sr) * CATW + k0s + sq;
    const unsigned short* aRow1 = catb + (size_t)(rowBase + 64 + sr) * CATW + k0s + sq;
    const unsigned short* bRow  = wob  + (size_t)(colBase + sr) * CATW + k0s + sq;

    f32x4 acc[4][2];
    #pragma unroll
    for (int i = 0; i < 4; ++i)
        #pragma unroll
        for (int j = 0; j < 2; ++j)
            acc[i][j] = (f32x4){0.f, 0.f, 0.f, 0.f};

    const int kg = (lane >> 4) * 8;
    const int rr = lane & 15;

    for (int k0 = 0; k0 < OKSTEP; k0 += 32) {
        bf16x8 a0 = *(const bf16x8*)(aRow0 + k0);
        bf16x8 a1 = *(const bf16x8*)(aRow1 + k0);
        bf16x8 b0 = *(const bf16x8*)(bRow  + k0);
        __syncthreads();
        *(bf16x8*)&As[sr][sq]      = a0;
        *(bf16x8*)&As[64 + sr][sq] = a1;
        *(bf16x8*)&Bs[sr][sq]      = b0;
        __syncthreads();
        bf16x8 bfr[2], afr[4];
        #pragma unroll
        for (int fc = 0; fc < 2; ++fc)
            bfr[fc] = *(const bf16x8*)&Bs[wc*32 + fc*16 + rr][kg];
        #pragma unroll
        for (int fr = 0; fr < 4; ++fr)
            afr[fr] = *(const bf16x8*)&As[wr*64 + fr*16 + rr][kg];
        #pragma unroll
        for (int fr = 0; fr < 4; ++fr)
            #pragma unroll
            for (int fc = 0; fc < 2; ++fc)
                acc[fr][fc] = __builtin_amdgcn_mfma_f32_16x16x32_bf16(
                    afr[fr], bfr[fc], acc[fr][fc], 0, 0, 0);
    }

    float* dst = parts + (size_t)blockIdx.z * MTOK * 384;
    const int cRowL = (lane >> 4) * 4;
    const int cColL = lane & 15;
    #pragma unroll
    for (int fr = 0; fr < 4; ++fr) {
        #pragma unroll
        for (int fc = 0; fc < 2; ++fc) {
            int col = colBase + wc*32 + fc*16 + cColL;
            int row0 = rowBase + wr*64 + fr*16 + cRowL;
            #pragma unroll
            for (int g = 0; g < 4; ++g)
                dst[(size_t)(row0 + g) * 384 + col] = acc[fr][fc][g];
        }
    }
}

__global__ __launch_bounds__(256) void reduce_splitk(
    const float* __restrict__ parts, const float* __restrict__ bias,
    float* __restrict__ out)
{
    const int i4 = blockIdx.x * 256 + threadIdx.x;   // float4 index
    const int TOT4 = MTOK * 384 / 4;
    if (i4 >= TOT4) return;
    const int c4 = i4 % (384 / 4);
    float4 acc = *(const float4*)(bias + c4 * 4);
    #pragma unroll
    for (int s = 0; s < OSK; ++s) {
        float4 p = *(const float4*)(parts + (size_t)s * MTOK * 384 + (size_t)i4 * 4);
        acc.x += p.x; acc.y += p.y; acc.z += p.z; acc.w += p.w;
    }
    *(float4*)(out + (size_t)i4 * 4) = acc;
}

// ------------- fused top-K (blocks [0,MTOK)) + point transform (blocks [MTOK,2*MTOK)) -------------
__global__ __launch_bounds__(256) void topk_pt(
    const float* __restrict__ trans,
    int* __restrict__ nidx,
    const float* __restrict__ lin,
    const float* __restrict__ rot,
    float* __restrict__ q_pts,
    float* __restrict__ k_pts,
    float* __restrict__ v_pts)
{
    __shared__ float t3[3 * NN];
    __shared__ unsigned long long keys[NN];
    __shared__ unsigned int hist[4][256];
    __shared__ unsigned int warp_sums[4];
    __shared__ unsigned int s_seldig, s_selexc, s_selcnt, out_cnt;
    __shared__ unsigned long long s_pivot;
    __shared__ int s_done;

    const int tid = threadIdx.x;

    if (blockIdx.x >= MTOK) {
        // ---- point transform path (no barriers, no LDS use)
        const int m = blockIdx.x - MTOK;
        const int j = tid;
        if (j < 192) {
            const float* R = rot + (size_t)m * 9;
            const float* T = trans + (size_t)m * 3;
            const float* L = lin + (size_t)m * LINW;
            float p0, p1, p2;
            if (j < 48) {
                p0 = L[576 + j]; p1 = L[576 + 48 + j]; p2 = L[576 + 96 + j];
            } else {
                int j2 = j - 48;                     // 0..143
                p0 = L[720 + j2]; p1 = L[720 + 144 + j2]; p2 = L[720 + 288 + j2];
            }
            float ox = R[0]*p0 + R[1]*p1 + R[2]*p2 + T[0];
            float oy = R[3]*p0 + R[4]*p1 + R[5]*p2 + T[1];
            float oz = R[6]*p0 + R[7]*p1 + R[8]*p2 + T[2];
            if (j < 48) {
                float* o = q_pts + (size_t)m * 144 + 3 * j;
                o[0] = ox; o[1] = oy; o[2] = oz;
            } else {
                int j2 = j - 48, h = j2 / 12, pp = j2 % 12;
                if (pp < PQD) {
                    float* o = k_pts + (size_t)m * 144 + ((h*PQD + pp) * 3);
                    o[0] = ox; o[1] = oy; o[2] = oz;
                } else {
                    float* o = v_pts + (size_t)m * 288 + ((h*PVD + pp - PQD) * 3);
                    o[0] = ox; o[1] = oy; o[2] = oz;
                }
            }
        }
        return;
    }

    // ---- top-K radix-select path (d^2 key; per-wave sub-hists)
    const int m = blockIdx.x, b = m / NN, n = m % NN;
    const int lane = tid & 63, wid = tid >> 6;

    if (tid == 0) { s_done = 0; out_cnt = 0; }
    for (int i = tid; i < 3 * NN; i += 256) t3[i] = trans[(size_t)b * 3 * NN + i];
    __syncthreads();
    const float tx = t3[n*3], ty = t3[n*3+1], tz = t3[n*3+2];
    for (int j = tid; j < NN; j += 256) {
        float dx = tx - t3[j*3], dy = ty - t3[j*3+1], dz = tz - t3[j*3+2];
        float d = dx*dx + dy*dy + dz*dz;          // rank-equivalent to sqrt
        keys[j] = ((unsigned long long)__float_as_uint(d) << 32) | (unsigned)j;
    }

    unsigned long long hi = 0;
    int rank = 0;
    const int target = KNB - 1;
    for (int d = 7; d >= 0; --d) {
        __syncthreads();
        if (s_done) break;
        const int shift = d * 8;
        for (int i = tid; i < 1024; i += 256) ((unsigned int*)hist)[i] = 0;
        __syncthreads();
        for (int j = tid; j < NN; j += 256) {
            unsigned long long key = keys[j];
            bool match = (d == 7) || ((key >> (shift + 8)) == hi);
            if (match) atomicAdd(&hist[wid][(unsigned)(key >> shift) & 0xffu], 1u);
        }
        __syncthreads();
        unsigned int v = hist[0][tid] + hist[1][tid] + hist[2][tid] + hist[3][tid];
        unsigned int inc = v;
        #pragma unroll
        for (int off = 1; off < 64; off <<= 1) {
            unsigned int nv = __shfl_up(inc, off);
            if (lane >= off) inc += nv;
        }
        if (lane == 63) warp_sums[wid] = inc;
        __syncthreads();
        unsigned int woff = 0;
        for (int w = 0; w < wid; ++w) woff += warp_sums[w];
        unsigned int exc = woff + inc - v;
        int t = target - rank;
        if ((int)exc <= t && t < (int)(exc + v)) {
            s_seldig = (unsigned)tid; s_selexc = exc; s_selcnt = v;
        }
        __syncthreads();
        hi = (hi << 8) | (unsigned long long)s_seldig;
        rank += (int)s_selexc;
        if (s_selcnt == 1u) {
            for (int j = tid; j < NN; j += 256) {
                unsigned long long key = keys[j];
                if ((key >> shift) == hi) s_pivot = key;
            }
            if (tid == 0) s_done = 1;
        } else if (d == 0) {
            if (tid == 0) { s_pivot = hi; s_done = 1; }
        }
    }
    __syncthreads();
    const unsigned long long pivot = s_pivot;
    for (int j = tid; j < NN; j += 256) {
        unsigned long long key = keys[j];
        if (key <= pivot) {
            unsigned p = atomicAdd(&out_cnt, 1u);
            nidx[(size_t)m * KNB + p] = (int)(key & 0xffffffffu);
        }
    }
}

// ------------- attention per token (round-7 proven version; writes cat in bf16) -------------
__global__ __launch_bounds__(256) void attn_kernel(
    const float* __restrict__ lin,     // q at +0, kv at +192 (per 1152-row)
    const float* __restrict__ q_pts,
    const float* __restrict__ k_pts,
    const float* __restrict__ v_pts,
    const int*   __restrict__ nidx,
    const float* __restrict__ z,       // (B, 512, 512, 128)
    const float* __restrict__ Wb,      // (12, 128)
    const float* __restrict__ bbv,     // (12)
    const float* __restrict__ hwin,    // (12)
    const float* __restrict__ mask,    // (B, N)
    const float* __restrict__ rot,
    const float* __restrict__ trans,
    unsigned short* __restrict__ cat)  // (M, 2112) bf16
{
    __shared__ __align__(16) float zn[KNB][CZP];     // 26.4 KB, padded rows
    __shared__ __align__(16) float WbS[HH][CZP];     // 6.3 KB
    __shared__ float aP[HH][KNB + 2];
    __shared__ __align__(16) float qloc[192];
    __shared__ __align__(16) float qp[144];
    __shared__ int   nk[KNB];
    __shared__ float maskn[KNB];
    __shared__ float hwS[HH];
    __shared__ __align__(16) float opt[288];

    const int m = blockIdx.x;
    const int b = m / NN, n = m % NN;
    const int tid = threadIdx.x;
    const int lane = tid & 63, wid = tid >> 6;

    if (tid < KNB) nk[tid] = nidx[(size_t)m * KNB + tid];
    __syncthreads();

    for (int i = tid; i < HH * CZD; i += 256) WbS[i / CZD][i % CZD] = Wb[i];
    for (int i = tid; i < 192; i += 256) qloc[i] = lin[(size_t)m * LINW + i];
    for (int i = tid; i < 144; i += 256) qp[i] = q_pts[(size_t)m * 144 + i];
    if (tid < HH) hwS[tid] = log1pf(expf(hwin[tid])) * 0.13608276348795434f; // sqrt(1/54)
    if (tid < KNB) maskn[tid] = 100000.0f * (mask[m] * mask[(size_t)b * NN + nk[tid]] - 1.0f);
    {
        const int sub = lane >> 5, l32 = lane & 31;
        for (int k = wid * 2 + sub; k < KNB; k += 8) {
            const float* zr = z + (((size_t)b * HALFN + (n & (HALFN-1))) * HALFN + (nk[k] & (HALFN-1))) * CZD;
            float4 v4 = *(const float4*)(zr + l32 * 4);
            *(float4*)&zn[k][l32 * 4] = v4;
        }
    }
    __syncthreads();

    // logits
    for (int idx = tid; idx < HH * KNB; idx += 256) {
        int k = idx / HH, h = idx % HH;
        int mk = b * NN + nk[k];
        const float* kvr = lin + (size_t)mk * LINW + 192 + h * 32;
        float qk = 0.f;
        #pragma unroll
        for (int c4 = 0; c4 < 4; ++c4) {
            float4 kv4 = *(const float4*)(kvr + c4 * 4);
            float4 q4  = *(const float4*)&qloc[h * 16 + c4 * 4];
            qk += q4.x*kv4.x + q4.y*kv4.y + q4.z*kv4.z + q4.w*kv4.w;
        }
        const float* kpr = k_pts + (size_t)mk * 144 + h * 12;
        float kp[12], qv[12];
        *(float4*)&kp[0] = *(const float4*)(kpr);
        *(float4*)&kp[4] = *(const float4*)(kpr + 4);
        *(float4*)&kp[8] = *(const float4*)(kpr + 8);
        *(float4*)&qv[0] = *(const float4*)&qp[h*12];
        *(float4*)&qv[4] = *(const float4*)&qp[h*12 + 4];
        *(float4*)&qv[8] = *(const float4*)&qp[h*12 + 8];
        float d2s = 0.f;
        #pragma unroll
        for (int e = 0; e < 12; ++e) { float dd = qv[e] - kp[e]; d2s += dd*dd; }
        float4 acc4 = {0.f, 0.f, 0.f, 0.f};
        #pragma unroll 8
        for (int c4 = 0; c4 < 32; ++c4) {
            float4 z4 = *(const float4*)&zn[k][c4 * 4];
            float4 w4 = *(const float4*)&WbS[h][c4 * 4];
            acc4.x += z4.x*w4.x; acc4.y += z4.y*w4.y;
            acc4.z += z4.z*w4.z; acc4.w += z4.w*w4.w;
        }
        float bp = bbv[h] + acc4.x + acc4.y + acc4.z + acc4.w;
        aP[h][k] = qk * 0.14433756729740643f      // sqrt(1/(3*16))
                 + 0.5773502691896258f * bp       // sqrt(1/3)
                 - 0.5f * hwS[h] * d2s
                 + maskn[k];
    }
    __syncthreads();

    // softmax over k per head (wave-parallel, lanes 0..49 hold values)
    for (int h = wid; h < HH; h += 4) {
        float v = (lane < KNB) ? aP[h][lane] : -1e30f;
        float mx = v;
        #pragma unroll
        for (int off = 32; off; off >>= 1) mx = fmaxf(mx, __shfl_xor(mx, off));
        float e = (lane < KNB) ? expf(v - mx) : 0.f;
        float s = e;
        #pragma unroll
        for (int off = 32; off; off >>= 1) s += __shfl_xor(s, off);
        if (lane < KNB) aP[h][lane] = e / s;
    }
    __syncthreads();

    // o (48 float4) and o_pt raw (72 float4)
    if (tid < 120) {
        float4 acc = {0.f, 0.f, 0.f, 0.f};
        if (tid < 48) {
            int h = tid >> 2, c4 = tid & 3;
            for (int k = 0; k < KNB; ++k) {
                int mk = b * NN + nk[k];
                float4 v4 = *(const float4*)(lin + (size_t)mk * LINW + 192 + h*32 + 16 + c4*4);
                float a = aP[h][k];
                acc.x += a*v4.x; acc.y += a*v4.y; acc.z += a*v4.z; acc.w += a*v4.w;
            }
            us4 o = { f2b(acc.x), f2b(acc.y), f2b(acc.z), f2b(acc.w) };
            *(us4*)(cat + (size_t)m * CATW + tid * 4) = o;
        } else {
            int u2 = tid - 48;                   // 0..71
            int h = (u2 * 4) / 24, r = (u2 * 4) % 24;
            for (int k = 0; k < KNB; ++k) {
                int mk = b * NN + nk[k];
                float4 v4 = *(const float4*)(v_pts + (size_t)mk * 288 + h*24 + r);
                float a = aP[h][k];
                acc.x += a*v4.x; acc.y += a*v4.y; acc.z += a*v4.z; acc.w += a*v4.w;
            }
            *(float4*)&opt[u2 * 4] = acc;
        }
    }
    __syncthreads();

    // inverse frame transform + norm
    if (tid < 96) {
        int hp = tid;
        float x = opt[hp*3+0] - trans[(size_t)m*3+0];
        float y = opt[hp*3+1] - trans[(size_t)m*3+1];
        float z0 = opt[hp*3+2] - trans[(size_t)m*3+2];
        const float* R = rot + (size_t)m * 9;
        float o0 = R[0]*x + R[3]*y + R[6]*z0;   // rot^T
        float o1 = R[1]*x + R[4]*y + R[7]*z0;
        float o2 = R[2]*x + R[5]*y + R[8]*z0;
        float nrm = sqrtf(o0*o0 + o1*o1 + o2*o2 + 1e-8f);
        unsigned short* c0 = cat + (size_t)m * CATW;
        c0[192 + hp] = f2b(o0);
        c0[288 + hp] = f2b(o1);
        c0[384 + hp] = f2b(o2);
        c0[480 + hp] = f2b(nrm);
    }

    // o_pair: 12 heads x 32 float4 columns from LDS zn
    for (int u = tid; u < HH * 32; u += 256) {
        int h = u >> 5, c4 = u & 31;
        float4 acc = {0.f, 0.f, 0.f, 0.f};
        for (int k = 0; k < KNB; ++k) {
            float a = aP[h][k];
            float4 z4 = *(const float4*)&zn[k][c4 * 4];
            acc.x += a*z4.x; acc.y += a*z4.y; acc.z += a*z4.z; acc.w += a*z4.w;
        }
        us4 o = { f2b(acc.x), f2b(acc.y), f2b(acc.z), f2b(acc.w) };
        *(us4*)(cat + (size_t)m * CATW + 576 + h * 128 + c4 * 4) = o;
    }
}

extern "C" void kernel_launch(void* const* d_in, const int* in_sizes, int n_in,
                              void* d_out, int out_size, void* d_ws, size_t ws_size,
                              hipStream_t stream) {
    const float* s     = (const float*)d_in[0];
    const float* z     = (const float*)d_in[1];
    const float* rot   = (const float*)d_in[2];
    const float* trans = (const float*)d_in[3];
    const float* mask  = (const float*)d_in[4];
    // d_in[5] rel_pos unused
    const float* Wq    = (const float*)d_in[6];
    const float* bq    = (const float*)d_in[7];
    const float* Wkv   = (const float*)d_in[8];
    const float* bkv   = (const float*)d_in[9];
    const float* Wqp   = (const float*)d_in[10];
    const float* bqp   = (const float*)d_in[11];
    const float* Wkvp  = (const float*)d_in[12];
    const float* bkvp  = (const float*)d_in[13];
    const float* Wb    = (const float*)d_in[14];
    const float* bb    = (const float*)d_in[15];
    const float* hw    = (const float*)d_in[16];
    const float* Wout  = (const float*)d_in[17];
    const float* bout  = (const float*)d_in[18];
    float* out = (float*)d_out;

    float* ws    = (float*)d_ws;
    float* lin   = ws;                              // 2048*1152 f32
    float* qpts  = lin  + (size_t)MTOK * LINW;      // 2048*144
    float* kpts  = qpts + (size_t)MTOK * 144;       // 2048*144
    float* vpts  = kpts + (size_t)MTOK * 144;       // 2048*288
    int*   nidxb = (int*)(vpts + (size_t)MTOK * 288);
    unsigned short* catb = (unsigned short*)(nidxb + (size_t)MTOK * KNB); // 2048*2112 bf16
    unsigned short* wob  = catb + (size_t)MTOK * CATW;                    // 384*2112 bf16
    unsigned short* sb   = wob  + (size_t)384 * CATW;                     // 2048*384 bf16
    unsigned short* wpb  = sb   + (size_t)MTOK * CSD;                     // 1152*384 bf16
    float* parts = (float*)(wpb + (size_t)LINW * CSD);                    // OSK*2048*384 f32

    const int CV_TOT = CV_N0 + CV_N1 + CV_N2;
    convert_all<<<(CV_TOT + 255) / 256, 256, 0, stream>>>(s, Wq, Wkv, Wqp, Wkvp, Wout,
                                                          sb, wpb, wob);
    dim3 g1(MTOK / 128, LINW / 64);
    gemm_proj_mfma<<<g1, 256, 0, stream>>>(sb, wpb, bq, bkv, bqp, bkvp, lin);
    topk_pt<<<2 * MTOK, 256, 0, stream>>>(trans, nidxb, lin, rot, qpts, kpts, vpts);
    attn_kernel<<<MTOK, 256, 0, stream>>>(lin, qpts, kpts, vpts, nidxb, z, Wb, bb, hw,
                                          mask, rot, trans, catb);
    dim3 g2(MTOK / 128, 384 / 64, OSK);
    gemm_out_mfma<<<g2, 256, 0, stream>>>(catb, wob, parts);
    reduce_splitk<<<(MTOK * 384 / 4 + 255) / 256, 256, 0, stream>>>(parts, bout, out);
}

// Round 11
// 104.890 us; speedup vs baseline: 2.4137x; 1.3108x over previous
//
#include <hip/hip_runtime.h>
#include <math.h>

#define BB    2
#define NN    1024
#define CSD   384
#define CZD   128
#define CZP   132     // padded LDS row (bank spread)
#define CHD   16
#define HH    12
#define PQD   4
#define PVD   8
#define KNB   50
#define HALFN 512
#define MTOK  (BB*NN)
#define LINW  1152
#define CATW  2112
#define OSK   6       // split-K for bf16 out-GEMM
#define OKSTEP (CATW / OSK)   // 352 = 11*32

typedef __attribute__((ext_vector_type(8))) short    bf16x8;
typedef __attribute__((ext_vector_type(4))) float    f32x4;
typedef __attribute__((ext_vector_type(4))) unsigned short us4;

// fp32 -> bf16 round-to-nearest-even (finite inputs; no header dependency)
static __device__ __forceinline__ unsigned short f2b(float x) {
    unsigned u = __float_as_uint(x);
    unsigned rnd = 0x7fffu + ((u >> 16) & 1u);
    return (unsigned short)((u + rnd) >> 16);
}

// ------------- one-pass fp32 -> bf16 conversions: s, packed proj W, Wout -------------
#define CV_N0 (MTOK * CSD / 4)        // s
#define CV_N1 (LINW * CSD / 4)        // packed proj weights
#define CV_N2 (384 * CATW / 4)        // Wout
__global__ __launch_bounds__(256) void convert_all(
    const float* __restrict__ s,
    const float* __restrict__ Wq,  const float* __restrict__ Wkv,
    const float* __restrict__ Wqp, const float* __restrict__ Wkvp,
    const float* __restrict__ Wout,
    unsigned short* __restrict__ sb,
    unsigned short* __restrict__ wpb,
    unsigned short* __restrict__ wob)
{
    const int i4 = blockIdx.x * 256 + threadIdx.x;
    if (i4 < CV_N0) {
        float4 v = *(const float4*)(s + (size_t)i4 * 4);
        us4 o = { f2b(v.x), f2b(v.y), f2b(v.z), f2b(v.w) };
        *(us4*)(sb + (size_t)i4 * 4) = o;
    } else if (i4 < CV_N0 + CV_N1) {
        int j4 = i4 - CV_N0;
        int r = j4 / (CSD / 4), c4 = j4 % (CSD / 4);
        const float* W; int wr;
        if      (r < 192) { W = Wq;   wr = r;       }
        else if (r < 576) { W = Wkv;  wr = r - 192; }
        else if (r < 720) { W = Wqp;  wr = r - 576; }
        else              { W = Wkvp; wr = r - 720; }
        float4 v = *(const float4*)(W + (size_t)wr * CSD + c4 * 4);
        us4 o = { f2b(v.x), f2b(v.y), f2b(v.z), f2b(v.w) };
        *(us4*)(wpb + (size_t)r * CSD + c4 * 4) = o;
    } else if (i4 < CV_N0 + CV_N1 + CV_N2) {
        int j4 = i4 - CV_N0 - CV_N1;
        float4 v = *(const float4*)(Wout + (size_t)j4 * 4);
        us4 o = { f2b(v.x), f2b(v.y), f2b(v.z), f2b(v.w) };
        *(us4*)(wob + (size_t)j4 * 4) = o;
    }
}

// ------------- bf16 MFMA projection GEMM: lin = sb @ wpb^T + bias (f32 out) -------------
__global__ __launch_bounds__(256) void gemm_proj_mfma(
    const unsigned short* __restrict__ sb,     // (2048, 384) bf16
    const unsigned short* __restrict__ wpb,    // (1152, 384) bf16
    const float* __restrict__ bq,  const float* __restrict__ bkv,
    const float* __restrict__ bqp, const float* __restrict__ bkvp,
    float* __restrict__ lin)                   // (2048, 1152) f32
{
    __shared__ unsigned short As[128][40];
    __shared__ unsigned short Bs[64][40];
    const int tid = threadIdx.x;
    const int lane = tid & 63, wv = tid >> 6;
    const int wr = wv >> 1, wc = wv & 1;
    const int rowBase = blockIdx.x * 128;
    const int colBase = blockIdx.y * 64;
    const int sr = tid >> 2;
    const int sq = (tid & 3) * 8;
    const unsigned short* aRow0 = sb  + (size_t)(rowBase + sr) * CSD + sq;
    const unsigned short* aRow1 = sb  + (size_t)(rowBase + 64 + sr) * CSD + sq;
    const unsigned short* bRow  = wpb + (size_t)(colBase + sr) * CSD + sq;

    f32x4 acc[4][2];
    #pragma unroll
    for (int i = 0; i < 4; ++i)
        #pragma unroll
        for (int j = 0; j < 2; ++j)
            acc[i][j] = (f32x4){0.f, 0.f, 0.f, 0.f};

    const int kg = (lane >> 4) * 8;
    const int rr = lane & 15;

    for (int k0 = 0; k0 < CSD; k0 += 32) {
        bf16x8 a0 = *(const bf16x8*)(aRow0 + k0);
        bf16x8 a1 = *(const bf16x8*)(aRow1 + k0);
        bf16x8 b0 = *(const bf16x8*)(bRow  + k0);
        __syncthreads();
        *(bf16x8*)&As[sr][sq]      = a0;
        *(bf16x8*)&As[64 + sr][sq] = a1;
        *(bf16x8*)&Bs[sr][sq]      = b0;
        __syncthreads();
        bf16x8 bfr[2], afr[4];
        #pragma unroll
        for (int fc = 0; fc < 2; ++fc)
            bfr[fc] = *(const bf16x8*)&Bs[wc*32 + fc*16 + rr][kg];
        #pragma unroll
        for (int fr = 0; fr < 4; ++fr)
            afr[fr] = *(const bf16x8*)&As[wr*64 + fr*16 + rr][kg];
        #pragma unroll
        for (int fr = 0; fr < 4; ++fr)
            #pragma unroll
            for (int fc = 0; fc < 2; ++fc)
                acc[fr][fc] = __builtin_amdgcn_mfma_f32_16x16x32_bf16(
                    afr[fr], bfr[fc], acc[fr][fc], 0, 0, 0);
    }

    const int cRowL = (lane >> 4) * 4;
    const int cColL = lane & 15;
    #pragma unroll
    for (int fc = 0; fc < 2; ++fc) {
        int col = colBase + wc*32 + fc*16 + cColL;
        float bia;
        if      (col < 192) bia = bq[col];
        else if (col < 576) bia = bkv[col - 192];
        else if (col < 720) bia = bqp[col - 576];
        else                bia = bkvp[col - 720];
        #pragma unroll
        for (int fr = 0; fr < 4; ++fr) {
            int row0 = rowBase + wr*64 + fr*16 + cRowL;
            #pragma unroll
            for (int g = 0; g < 4; ++g)
                lin[(size_t)(row0 + g) * LINW + col] = acc[fr][fc][g] + bia;
        }
    }
}

// ------------- bf16 MFMA out-GEMM: parts[z] = catb @ wob^T over k-chunk -------------
__global__ __launch_bounds__(256) void gemm_out_mfma(
    const unsigned short* __restrict__ catb,   // (2048, 2112) bf16
    const unsigned short* __restrict__ wob,    // (384, 2112) bf16
    float* __restrict__ parts)
{
    __shared__ unsigned short As[128][40];
    __shared__ unsigned short Bs[64][40];
    const int tid = threadIdx.x;
    const int lane = tid & 63, wv = tid >> 6;
    const int wr = wv >> 1, wc = wv & 1;
    const int rowBase = blockIdx.x * 128;
    const int colBase = blockIdx.y * 64;
    const int k0s = blockIdx.z * OKSTEP;
    const int sr = tid >> 2;
    const int sq = (tid & 3) * 8;
    const unsigned short* aRow0 = catb + (size_t)(rowBase + sr) * CATW + k0s + sq;
    const unsigned short* aRow1 = catb + (size_t)(rowBase + 64 + sr) * CATW + k0s + sq;
    const unsigned short* bRow  = wob  + (size_t)(colBase + sr) * CATW + k0s + sq;

    f32x4 acc[4][2];
    #pragma unroll
    for (int i = 0; i < 4; ++i)
        #pragma unroll
        for (int j = 0; j < 2; ++j)
            acc[i][j] = (f32x4){0.f, 0.f, 0.f, 0.f};

    const int kg = (lane >> 4) * 8;
    const int rr = lane & 15;

    for (int k0 = 0; k0 < OKSTEP; k0 += 32) {
        bf16x8 a0 = *(const bf16x8*)(aRow0 + k0);
        bf16x8 a1 = *(const bf16x8*)(aRow1 + k0);
        bf16x8 b0 = *(const bf16x8*)(bRow  + k0);
        __syncthreads();
        *(bf16x8*)&As[sr][sq]      = a0;
        *(bf16x8*)&As[64 + sr][sq] = a1;
        *(bf16x8*)&Bs[sr][sq]      = b0;
        __syncthreads();
        bf16x8 bfr[2], afr[4];
        #pragma unroll
        for (int fc = 0; fc < 2; ++fc)
            bfr[fc] = *(const bf16x8*)&Bs[wc*32 + fc*16 + rr][kg];
        #pragma unroll
        for (int fr = 0; fr < 4; ++fr)
            afr[fr] = *(const bf16x8*)&As[wr*64 + fr*16 + rr][kg];
        #pragma unroll
        for (int fr = 0; fr < 4; ++fr)
            #pragma unroll
            for (int fc = 0; fc < 2; ++fc)
                acc[fr][fc] = __builtin_amdgcn_mfma_f32_16x16x32_bf16(
                    afr[fr], bfr[fc], acc[fr][fc], 0, 0, 0);
    }

    float* dst = parts + (size_t)blockIdx.z * MTOK * 384;
    const int cRowL = (lane >> 4) * 4;
    const int cColL = lane & 15;
    #pragma unroll
    for (int fr = 0; fr < 4; ++fr) {
        #pragma unroll
        for (int fc = 0; fc < 2; ++fc) {
            int col = colBase + wc*32 + fc*16 + cColL;
            int row0 = rowBase + wr*64 + fr*16 + cRowL;
            #pragma unroll
            for (int g = 0; g < 4; ++g)
                dst[(size_t)(row0 + g) * 384 + col] = acc[fr][fc][g];
        }
    }
}

__global__ __launch_bounds__(256) void reduce_splitk(
    const float* __restrict__ parts, const float* __restrict__ bias,
    float* __restrict__ out)
{
    const int i4 = blockIdx.x * 256 + threadIdx.x;   // float4 index
    const int TOT4 = MTOK * 384 / 4;
    if (i4 >= TOT4) return;
    const int c4 = i4 % (384 / 4);
    float4 acc = *(const float4*)(bias + c4 * 4);
    #pragma unroll
    for (int s = 0; s < OSK; ++s) {
        float4 p = *(const float4*)(parts + (size_t)s * MTOK * 384 + (size_t)i4 * 4);
        acc.x += p.x; acc.y += p.y; acc.z += p.z; acc.w += p.w;
    }
    *(float4*)(out + (size_t)i4 * 4) = acc;
}

// ------------- point transform: rot @ p + trans -------------
__global__ void point_transform(const float* __restrict__ lin,
                                const float* __restrict__ rot,
                                const float* __restrict__ trans,
                                float* __restrict__ q_pts,
                                float* __restrict__ k_pts,
                                float* __restrict__ v_pts)
{
    const int m = blockIdx.x;
    const int j = threadIdx.x;   // 0..191
    const float* R = rot + (size_t)m * 9;
    const float* T = trans + (size_t)m * 3;
    const float* L = lin + (size_t)m * LINW;
    float p0, p1, p2;
    if (j < 48) {
        p0 = L[576 + j]; p1 = L[576 + 48 + j]; p2 = L[576 + 96 + j];
    } else {
        int j2 = j - 48;                     // 0..143
        p0 = L[720 + j2]; p1 = L[720 + 144 + j2]; p2 = L[720 + 288 + j2];
    }
    float ox = R[0]*p0 + R[1]*p1 + R[2]*p2 + T[0];
    float oy = R[3]*p0 + R[4]*p1 + R[5]*p2 + T[1];
    float oz = R[6]*p0 + R[7]*p1 + R[8]*p2 + T[2];
    if (j < 48) {
        float* o = q_pts + (size_t)m * 144 + 3 * j;
        o[0] = ox; o[1] = oy; o[2] = oz;
    } else {
        int j2 = j - 48, h = j2 / 12, pp = j2 % 12;
        if (pp < PQD) {
            float* o = k_pts + (size_t)m * 144 + ((h*PQD + pp) * 3);
            o[0] = ox; o[1] = oy; o[2] = oz;
        } else {
            float* o = v_pts + (size_t)m * 288 + ((h*PVD + pp - PQD) * 3);
            o[0] = ox; o[1] = oy; o[2] = oz;
        }
    }
}

// ------------- fused top-K + attention per token -------------
// Phase 1: radix-select top-50 neighbors into nk[] (LDS; scratch unions with zn).
// Phase 2: round-9-proven attention; o_pair restructured to 2 heads/thread.
__global__ __launch_bounds__(256) void attn_topk_kernel(
    const float* __restrict__ lin,     // q at +0, kv at +192 (per 1152-row)
    const float* __restrict__ q_pts,
    const float* __restrict__ k_pts,
    const float* __restrict__ v_pts,
    const float* __restrict__ trans,
    const float* __restrict__ z,       // (B, 512, 512, 128)
    const float* __restrict__ Wb,      // (12, 128)
    const float* __restrict__ bbv,     // (12)
    const float* __restrict__ hwin,    // (12)
    const float* __restrict__ mask,    // (B, N)
    const float* __restrict__ rot,
    unsigned short* __restrict__ cat)  // (M, 2112) bf16
{
    union TopZ {
        struct {
            float t3[3 * NN];                  // 12288 B
            unsigned long long keys[NN];       //  8192 B
            unsigned int hist[4][256];         //  4096 B
        } t;
        float zn[KNB][CZP];                    // 26400 B
    };
    __shared__ __align__(16) union TopZ u;
    __shared__ __align__(16) float WbS[HH][CZP];
    __shared__ float aP[HH][KNB + 2];
    __shared__ __align__(16) float qloc[192];
    __shared__ __align__(16) float qp[144];
    __shared__ int   nk[KNB];
    __shared__ float maskn[KNB];
    __shared__ float hwS[HH];
    __shared__ __align__(16) float opt[288];
    __shared__ unsigned int warp_sums[4];
    __shared__ unsigned int s_seldig, s_selexc, s_selcnt, out_cnt;
    __shared__ unsigned long long s_pivot;
    __shared__ int s_done;

    const int m = blockIdx.x;
    const int b = m / NN, n = m % NN;
    const int tid = threadIdx.x;
    const int lane = tid & 63, wid = tid >> 6;

    // independent loads (overlap with topk phase; separate LDS from union)
    for (int i = tid; i < HH * CZD; i += 256) WbS[i / CZD][i % CZD] = Wb[i];
    for (int i = tid; i < 192; i += 256) qloc[i] = lin[(size_t)m * LINW + i];
    for (int i = tid; i < 144; i += 256) qp[i] = q_pts[(size_t)m * 144 + i];
    if (tid < HH) hwS[tid] = log1pf(expf(hwin[tid])) * 0.13608276348795434f; // sqrt(1/54)

    // ---------- Phase 1: top-K radix select (d^2 keys; set is order-invariant) ----------
    if (tid == 0) { s_done = 0; out_cnt = 0; }
    for (int i = tid; i < 3 * NN; i += 256) u.t.t3[i] = trans[(size_t)b * 3 * NN + i];
    __syncthreads();
    {
        const float tx = u.t.t3[n*3], ty = u.t.t3[n*3+1], tz = u.t.t3[n*3+2];
        for (int j = tid; j < NN; j += 256) {
            float dx = tx - u.t.t3[j*3], dy = ty - u.t.t3[j*3+1], dz = tz - u.t.t3[j*3+2];
            float d = dx*dx + dy*dy + dz*dz;
            u.t.keys[j] = ((unsigned long long)__float_as_uint(d) << 32) | (unsigned)j;
        }
    }
    {
        unsigned long long hi = 0;
        int rank = 0;
        const int target = KNB - 1;
        for (int d = 7; d >= 0; --d) {
            __syncthreads();
            if (s_done) break;
            const int shift = d * 8;
            for (int i = tid; i < 1024; i += 256) ((unsigned int*)u.t.hist)[i] = 0;
            __syncthreads();
            for (int j = tid; j < NN; j += 256) {
                unsigned long long key = u.t.keys[j];
                bool match = (d == 7) || ((key >> (shift + 8)) == hi);
                if (match) atomicAdd(&u.t.hist[wid][(unsigned)(key >> shift) & 0xffu], 1u);
            }
            __syncthreads();
            unsigned int v = u.t.hist[0][tid] + u.t.hist[1][tid]
                           + u.t.hist[2][tid] + u.t.hist[3][tid];
            unsigned int inc = v;
            #pragma unroll
            for (int off = 1; off < 64; off <<= 1) {
                unsigned int nv = __shfl_up(inc, off);
                if (lane >= off) inc += nv;
            }
            if (lane == 63) warp_sums[wid] = inc;
            __syncthreads();
            unsigned int woff = 0;
            for (int w = 0; w < wid; ++w) woff += warp_sums[w];
            unsigned int exc = woff + inc - v;
            int t = target - rank;
            if ((int)exc <= t && t < (int)(exc + v)) {
                s_seldig = (unsigned)tid; s_selexc = exc; s_selcnt = v;
            }
            __syncthreads();
            hi = (hi << 8) | (unsigned long long)s_seldig;
            rank += (int)s_selexc;
            if (s_selcnt == 1u) {
                for (int j = tid; j < NN; j += 256) {
                    unsigned long long key = u.t.keys[j];
                    if ((key >> shift) == hi) s_pivot = key;
                }
                if (tid == 0) s_done = 1;
            } else if (d == 0) {
                if (tid == 0) { s_pivot = hi; s_done = 1; }
            }
        }
        __syncthreads();
        const unsigned long long pivot = s_pivot;
        for (int j = tid; j < NN; j += 256) {
            unsigned long long key = u.t.keys[j];
            if (key <= pivot) {
                unsigned p = atomicAdd(&out_cnt, 1u);
                nk[p] = (int)(key & 0xffffffffu);
            }
        }
    }
    __syncthreads();   // nk complete; topk scratch dead -> zn may overwrite union

    // ---------- Phase 2: attention ----------
    if (tid < KNB) maskn[tid] = 100000.0f * (mask[m] * mask[(size_t)b * NN + nk[tid]] - 1.0f);
    {
        const int sub = lane >> 5, l32 = lane & 31;
        for (int k = wid * 2 + sub; k < KNB; k += 8) {
            const float* zr = z + (((size_t)b * HALFN + (n & (HALFN-1))) * HALFN + (nk[k] & (HALFN-1))) * CZD;
            float4 v4 = *(const float4*)(zr + l32 * 4);
            *(float4*)&u.zn[k][l32 * 4] = v4;
        }
    }
    __syncthreads();

    // logits
    for (int idx = tid; idx < HH * KNB; idx += 256) {
        int k = idx / HH, h = idx % HH;
        int mk = b * NN + nk[k];
        const float* kvr = lin + (size_t)mk * LINW + 192 + h * 32;
        float qk = 0.f;
        #pragma unroll
        for (int c4 = 0; c4 < 4; ++c4) {
            float4 kv4 = *(const float4*)(kvr + c4 * 4);
            float4 q4  = *(const float4*)&qloc[h * 16 + c4 * 4];
            qk += q4.x*kv4.x + q4.y*kv4.y + q4.z*kv4.z + q4.w*kv4.w;
        }
        const float* kpr = k_pts + (size_t)mk * 144 + h * 12;
        float kp[12], qv[12];
        *(float4*)&kp[0] = *(const float4*)(kpr);
        *(float4*)&kp[4] = *(const float4*)(kpr + 4);
        *(float4*)&kp[8] = *(const float4*)(kpr + 8);
        *(float4*)&qv[0] = *(const float4*)&qp[h*12];
        *(float4*)&qv[4] = *(const float4*)&qp[h*12 + 4];
        *(float4*)&qv[8] = *(const float4*)&qp[h*12 + 8];
        float d2s = 0.f;
        #pragma unroll
        for (int e = 0; e < 12; ++e) { float dd = qv[e] - kp[e]; d2s += dd*dd; }
        float4 acc4 = {0.f, 0.f, 0.f, 0.f};
        #pragma unroll 8
        for (int c4 = 0; c4 < 32; ++c4) {
            float4 z4 = *(const float4*)&u.zn[k][c4 * 4];
            float4 w4 = *(const float4*)&WbS[h][c4 * 4];
            acc4.x += z4.x*w4.x; acc4.y += z4.y*w4.y;
            acc4.z += z4.z*w4.z; acc4.w += z4.w*w4.w;
        }
        float bp = bbv[h] + acc4.x + acc4.y + acc4.z + acc4.w;
        aP[h][k] = qk * 0.14433756729740643f      // sqrt(1/(3*16))
                 + 0.5773502691896258f * bp       // sqrt(1/3)
                 - 0.5f * hwS[h] * d2s
                 + maskn[k];
    }
    __syncthreads();

    // softmax over k per head (wave-parallel, lanes 0..49 hold values)
    for (int h = wid; h < HH; h += 4) {
        float v = (lane < KNB) ? aP[h][lane] : -1e30f;
        float mx = v;
        #pragma unroll
        for (int off = 32; off; off >>= 1) mx = fmaxf(mx, __shfl_xor(mx, off));
        float e = (lane < KNB) ? expf(v - mx) : 0.f;
        float s = e;
        #pragma unroll
        for (int off = 32; off; off >>= 1) s += __shfl_xor(s, off);
        if (lane < KNB) aP[h][lane] = e / s;
    }
    __syncthreads();

    // o (48 float4) and o_pt raw (72 float4)
    if (tid < 120) {
        float4 acc = {0.f, 0.f, 0.f, 0.f};
        if (tid < 48) {
            int h = tid >> 2, c4 = tid & 3;
            for (int k = 0; k < KNB; ++k) {
                int mk = b * NN + nk[k];
                float4 v4 = *(const float4*)(lin + (size_t)mk * LINW + 192 + h*32 + 16 + c4*4);
                float a = aP[h][k];
                acc.x += a*v4.x; acc.y += a*v4.y; acc.z += a*v4.z; acc.w += a*v4.w;
            }
            us4 o = { f2b(acc.x), f2b(acc.y), f2b(acc.z), f2b(acc.w) };
            *(us4*)(cat + (size_t)m * CATW + tid * 4) = o;
        } else {
            int u2 = tid - 48;                   // 0..71
            int h = (u2 * 4) / 24, r = (u2 * 4) % 24;
            for (int k = 0; k < KNB; ++k) {
                int mk = b * NN + nk[k];
                float4 v4 = *(const float4*)(v_pts + (size_t)mk * 288 + h*24 + r);
                float a = aP[h][k];
                acc.x += a*v4.x; acc.y += a*v4.y; acc.z += a*v4.z; acc.w += a*v4.w;
            }
            *(float4*)&opt[u2 * 4] = acc;
        }
    }

    // o_pair: 2 heads per thread share each zn row read (192 threads: (hp, c4))
    if (tid < 192) {
        int hp = tid >> 5, c4 = tid & 31;    // hp 0..5 -> heads hp, hp+6
        float4 acc0 = {0.f, 0.f, 0.f, 0.f};
        float4 acc1 = {0.f, 0.f, 0.f, 0.f};
        for (int k = 0; k < KNB; ++k) {
            float a0 = aP[hp][k], a1 = aP[hp + 6][k];
            float4 z4 = *(const float4*)&u.zn[k][c4 * 4];
            acc0.x += a0*z4.x; acc0.y += a0*z4.y; acc0.z += a0*z4.z; acc0.w += a0*z4.w;
            acc1.x += a1*z4.x; acc1.y += a1*z4.y; acc1.z += a1*z4.z; acc1.w += a1*z4.w;
        }
        us4 o0 = { f2b(acc0.x), f2b(acc0.y), f2b(acc0.z), f2b(acc0.w) };
        us4 o1 = { f2b(acc1.x), f2b(acc1.y), f2b(acc1.z), f2b(acc1.w) };
        *(us4*)(cat + (size_t)m * CATW + 576 + hp * 128 + c4 * 4) = o0;
        *(us4*)(cat + (size_t)m * CATW + 576 + (hp + 6) * 128 + c4 * 4) = o1;
    }
    __syncthreads();

    // inverse frame transform + norm
    if (tid < 96) {
        int hp = tid;
        float x = opt[hp*3+0] - trans[(size_t)m*3+0];
        float y = opt[hp*3+1] - trans[(size_t)m*3+1];
        float z0 = opt[hp*3+2] - trans[(size_t)m*3+2];
        const float* R = rot + (size_t)m * 9;
        float o0 = R[0]*x + R[3]*y + R[6]*z0;   // rot^T
        float o1 = R[1]*x + R[4]*y + R[7]*z0;
        float o2 = R[2]*x + R[5]*y + R[8]*z0;
        float nrm = sqrtf(o0*o0 + o1*o1 + o2*o2 + 1e-8f);
        unsigned short* c0 = cat + (size_t)m * CATW;
        c0[192 + hp] = f2b(o0);
        c0[288 + hp] = f2b(o1);
        c0[384 + hp] = f2b(o2);
        c0[480 + hp] = f2b(nrm);
    }
}

extern "C" void kernel_launch(void* const* d_in, const int* in_sizes, int n_in,
                              void* d_out, int out_size, void* d_ws, size_t ws_size,
                              hipStream_t stream) {
    const float* s     = (const float*)d_in[0];
    const float* z     = (const float*)d_in[1];
    const float* rot   = (const float*)d_in[2];
    const float* trans = (const float*)d_in[3];
    const float* mask  = (const float*)d_in[4];
    // d_in[5] rel_pos unused
    const float* Wq    = (const float*)d_in[6];
    const float* bq    = (const float*)d_in[7];
    const float* Wkv   = (const float*)d_in[8];
    const float* bkv   = (const float*)d_in[9];
    const float* Wqp   = (const float*)d_in[10];
    const float* bqp   = (const float*)d_in[11];
    const float* Wkvp  = (const float*)d_in[12];
    const float* bkvp  = (const float*)d_in[13];
    const float* Wb    = (const float*)d_in[14];
    const float* bb    = (const float*)d_in[15];
    const float* hw    = (const float*)d_in[16];
    const float* Wout  = (const float*)d_in[17];
    const float* bout  = (const float*)d_in[18];
    float* out = (float*)d_out;

    float* ws    = (float*)d_ws;
    float* lin   = ws;                              // 2048*1152 f32
    float* qpts  = lin  + (size_t)MTOK * LINW;      // 2048*144
    float* kpts  = qpts + (size_t)MTOK * 144;       // 2048*144
    float* vpts  = kpts + (size_t)MTOK * 144;       // 2048*288
    unsigned short* catb = (unsigned short*)(vpts + (size_t)MTOK * 288);  // 2048*2112 bf16
    unsigned short* wob  = catb + (size_t)MTOK * CATW;                    // 384*2112 bf16
    unsigned short* sb   = wob  + (size_t)384 * CATW;                     // 2048*384 bf16
    unsigned short* wpb  = sb   + (size_t)MTOK * CSD;                     // 1152*384 bf16
    float* parts = (float*)(wpb + (size_t)LINW * CSD);                    // OSK*2048*384 f32

    const int CV_TOT = CV_N0 + CV_N1 + CV_N2;
    convert_all<<<(CV_TOT + 255) / 256, 256, 0, stream>>>(s, Wq, Wkv, Wqp, Wkvp, Wout,
                                                          sb, wpb, wob);
    dim3 g1(MTOK / 128, LINW / 64);
    gemm_proj_mfma<<<g1, 256, 0, stream>>>(sb, wpb, bq, bkv, bqp, bkvp, lin);
    point_transform<<<MTOK, 192, 0, stream>>>(lin, rot, trans, qpts, kpts, vpts);
    attn_topk_kernel<<<MTOK, 256, 0, stream>>>(lin, qpts, kpts, vpts, trans, z,
                                               Wb, bb, hw, mask, rot, catb);
    dim3 g2(MTOK / 128, 384 / 64, OSK);
    gemm_out_mfma<<<g2, 256, 0, stream>>>(catb, wob, parts);
    reduce_splitk<<<(MTOK * 384 / 4 + 255) / 256, 256, 0, stream>>>(parts, bout, out);
}